// Round 8
// baseline (199.339 us; speedup 1.0000x reference)
//
#include <hip/hip_runtime.h>
#include <hip/hip_bf16.h>
#include <stdint.h>

// Problem constants: B=4, S=2048, D=1024, H=16, HD=64
#define B_  4
#define S_  2048
#define D_  1024
#define H_  16
#define HD_ 64

typedef __attribute__((ext_vector_type(8))) short          s16x8;   // MFMA A/B frag (8 bf16)
typedef __attribute__((ext_vector_type(4))) float          f32x4;   // MFMA C/D frag
typedef __attribute__((ext_vector_type(8))) unsigned short u16x8;   // 16B bf16 chunk

__device__ __forceinline__ unsigned short f2bf(float f) {
  union { float f; unsigned int u; } v; v.f = f;
  unsigned int u = v.u;
  u += 0x7fffu + ((u >> 16) & 1u);       // RNE
  return (unsigned short)(u >> 16);
}

// async global->LDS, 16B per lane; LDS dest = wave-uniform base + lane*16
#define GLDS16(g, l)                                                           \
  __builtin_amdgcn_global_load_lds(                                            \
      (const __attribute__((address_space(1))) void*)(g),                      \
      (__attribute__((address_space(3))) void*)(l), 16, 0, 0)

// ---------------------------------------------------------------- converts
__global__ void k_cvt(const float* __restrict__ src, unsigned short* __restrict__ dst, int n4) {
  int i = blockIdx.x * blockDim.x + threadIdx.x;
  int stride = gridDim.x * blockDim.x;
  for (int j = i; j < n4; j += stride) {
    float4 v = reinterpret_cast<const float4*>(src)[j];
    ushort4 o;
    o.x = f2bf(v.x); o.y = f2bf(v.y); o.z = f2bf(v.z); o.w = f2bf(v.w);
    reinterpret_cast<ushort4*>(dst)[j] = o;
  }
}

// fp32 [R][C] -> bf16 [C][R]   (weights -> B^T layout for gemm-BT)
__global__ void k_tpose_cvt(const float* __restrict__ src, unsigned short* __restrict__ dst,
                            int R, int C) {
  __shared__ unsigned short tile[64][72];
  int c0 = blockIdx.x * 64, r0 = blockIdx.y * 64;
  int tx = threadIdx.x & 63, ty = threadIdx.x >> 6;
#pragma unroll
  for (int i = 0; i < 16; ++i) {
    int r = ty * 16 + i;
    tile[r][tx] = f2bf(src[(size_t)(r0 + r) * C + c0 + tx]);
  }
  __syncthreads();
#pragma unroll
  for (int i = 0; i < 16; ++i) {
    int c = ty * 16 + i;
    dst[(size_t)(c0 + c) * R + r0 + tx] = tile[tx][c];
  }
}

// bf16 V [BH][S][HD] -> Vt [BH][HD][S]
__global__ void k_tpose_v(const unsigned short* __restrict__ src, unsigned short* __restrict__ dst) {
  __shared__ unsigned short tile[64][72];
  int s0 = blockIdx.x * 64, bh = blockIdx.y;
  int tx = threadIdx.x & 63, ty = threadIdx.x >> 6;
  const unsigned short* sb = src + (size_t)bh * S_ * HD_;
  unsigned short*       db = dst + (size_t)bh * S_ * HD_;
#pragma unroll
  for (int i = 0; i < 16; ++i) {
    int r = ty * 16 + i;
    tile[r][tx] = sb[(size_t)(s0 + r) * HD_ + tx];
  }
  __syncthreads();
#pragma unroll
  for (int i = 0; i < 16; ++i) {
    int hd = ty * 16 + i;
    db[(size_t)hd * S_ + s0 + tx] = tile[tx][hd];
  }
}

// ---------------------------------------------------------------- GEMM core
// (unchanged from round 7: global_load_lds width=16, linear LDS dest,
//  source-side XOR chunk swizzle, one barrier per K-step)
__device__ __forceinline__ void gemm_core(const unsigned short* __restrict__ A,
                                          const unsigned short* __restrict__ Bt,
                                          int K, int m0, int n0,
                                          unsigned short* sm, f32x4 acc[4][4]) {
  const int t = threadIdx.x;
  const int w = t >> 6, l = t & 63;
  const int wm = w >> 1, wn = w & 1;
  const int lo = l & 15, hi = l >> 4;

  const int ci0 = w * 64 + l, ci1 = ci0 + 256;
  const int rA0 = ci0 >> 2, cA0 = (ci0 & 3) ^ ((rA0 >> 1) & 3);
  const int rA1 = ci1 >> 2, cA1 = (ci1 & 3) ^ ((rA1 >> 1) & 3);
  const unsigned short* gA0 = A  + (size_t)(m0 + rA0) * K + cA0 * 8;
  const unsigned short* gA1 = A  + (size_t)(m0 + rA1) * K + cA1 * 8;
  const unsigned short* gB0 = Bt + (size_t)(n0 + rA0) * K + cA0 * 8;
  const unsigned short* gB1 = Bt + (size_t)(n0 + rA1) * K + cA1 * 8;
  const int ldsA0 = (w * 64) * 8;          // wave-uniform LDS bases (shorts)
  const int ldsA1 = (256 + w * 64) * 8;

#pragma unroll
  for (int m = 0; m < 4; ++m)
#pragma unroll
    for (int n = 0; n < 4; ++n)
      acc[m][n] = (f32x4){0.f, 0.f, 0.f, 0.f};

  const int NT = K >> 5;  // BK = 32

  {
    unsigned short* b = sm;
    GLDS16(gA0, b + ldsA0);
    GLDS16(gA1, b + ldsA1);
    GLDS16(gB0, b + 4096 + ldsA0);
    GLDS16(gB1, b + 4096 + ldsA1);
  }

  for (int kt = 0; kt < NT; ++kt) {
    __syncthreads();   // vmcnt(0)+lgkmcnt(0) drain: buf[kt&1] staged, prev reads done
    if (kt + 1 < NT) {
      unsigned short* b = sm + ((kt + 1) & 1) * 8192;
      const int ko = (kt + 1) << 5;
      GLDS16(gA0 + ko, b + ldsA0);
      GLDS16(gA1 + ko, b + ldsA1);
      GLDS16(gB0 + ko, b + 4096 + ldsA0);
      GLDS16(gB1 + ko, b + 4096 + ldsA1);
    }
    const unsigned short* Ab = sm + (kt & 1) * 8192;
    const unsigned short* Bb = Ab + 4096;
    s16x8 af[4], bfr[4];
#pragma unroll
    for (int m = 0; m < 4; ++m) {
      int row = wm * 64 + m * 16 + lo;
      af[m] = *(const s16x8*)(Ab + row * 32 + ((hi ^ ((row >> 1) & 3)) << 3));
    }
#pragma unroll
    for (int n = 0; n < 4; ++n) {
      int row = wn * 64 + n * 16 + lo;
      bfr[n] = *(const s16x8*)(Bb + row * 32 + ((hi ^ ((row >> 1) & 3)) << 3));
    }
    __builtin_amdgcn_s_setprio(1);
#pragma unroll
    for (int m = 0; m < 4; ++m)
#pragma unroll
      for (int n = 0; n < 4; ++n)
        acc[m][n] = __builtin_amdgcn_mfma_f32_16x16x32_bf16(af[m], bfr[n], acc[m][n], 0, 0, 0);
    __builtin_amdgcn_s_setprio(0);
  }
}

// GEMM1: qkv = x @ W_attn + b ; scatter into Q/K/V [B,H,S,HD] bf16.
// Q is pre-scaled by 0.125*log2(e) so attention runs in exp2 domain.
__global__ __launch_bounds__(256, 3)
void k_gemm_qkv(const unsigned short* __restrict__ A, const unsigned short* __restrict__ Bt,
                const float* __restrict__ bias,
                unsigned short* __restrict__ Qh, unsigned short* __restrict__ Kh,
                unsigned short* __restrict__ Vh) {
  __shared__ unsigned short sm[2 * 8192];
  const int m0 = blockIdx.y * 128, n0 = blockIdx.x * 128;
  f32x4 acc[4][4];
  gemm_core(A, Bt, 1024, m0, n0, sm, acc);
  const int t = threadIdx.x, w = t >> 6, l = t & 63;
  const int wm = w >> 1, wn = w & 1, lo = l & 15, hi = l >> 4;
#pragma unroll
  for (int m = 0; m < 4; ++m)
#pragma unroll
    for (int n = 0; n < 4; ++n) {
      int col = n0 + wn * 64 + n * 16 + lo;           // 0..3071
      float bv = bias[col];
      int sel = col >> 10, cw = col & 1023, h = cw >> 6, hd = cw & 63;
      float scl = (sel == 0) ? 0.18033688011112042f : 1.0f;  // log2(e)/8
      unsigned short* dst = (sel == 0) ? Qh : ((sel == 1) ? Kh : Vh);
#pragma unroll
      for (int r = 0; r < 4; ++r) {
        int row = m0 + wm * 64 + m * 16 + hi * 4 + r;
        int b = row >> 11, s = row & 2047;
        dst[(((size_t)b * H_ + h) * S_ + s) * HD_ + hd] = f2bf((acc[m][n][r] + bv) * scl);
      }
    }
}

// GEMM2: out = ctx @ W_proj + b ; fp32 out
__global__ __launch_bounds__(256, 3)
void k_gemm_proj(const unsigned short* __restrict__ A, const unsigned short* __restrict__ Bt,
                 const float* __restrict__ bias, float* __restrict__ C, int N) {
  __shared__ unsigned short sm[2 * 8192];
  const int m0 = blockIdx.y * 128, n0 = blockIdx.x * 128;
  f32x4 acc[4][4];
  gemm_core(A, Bt, 1024, m0, n0, sm, acc);
  const int t = threadIdx.x, w = t >> 6, l = t & 63;
  const int wm = w >> 1, wn = w & 1, lo = l & 15, hi = l >> 4;
#pragma unroll
  for (int m = 0; m < 4; ++m)
#pragma unroll
    for (int n = 0; n < 4; ++n) {
      int col = n0 + wn * 64 + n * 16 + lo;
      float bv = bias[col];
#pragma unroll
      for (int r = 0; r < 4; ++r) {
        int row = m0 + wm * 64 + m * 16 + hi * 4 + r;
        C[(size_t)row * N + col] = acc[m][n][r] + bv;
      }
    }
}

// ---------------------------------------------------------------- attention
// Swapped QK^T (mfma(K,Q)); K rows LDS-permuted so the PV A-fragment is
// lane-resident after cvt_pk; G4 XOR chunk swizzle on K/V (0 conflicts);
// T13 defer-max; double-buffered LDS + T14 async-STAGE (1 barrier/tile);
// XCD swizzle (FETCH 24.6 MB measured, L2-resident K/V).
// Round-8: UNIFORM-WORK PAIRING. Round 7's makespan was set by the iq=15
// blocks (64 g-units) while short blocks idled their CUs (occupancy 19%).
// Now each block owns two 64-row q-subtiles (jp and 31-jp) of one head in
// ONE shared KV sweep: g=0 (rows 64*jp..) active for kt<=jp; g=1 (rows
// 64*(31-jp)..) active all nt=32-jp tiles. Per-block compute = 33 g-units,
// exactly uniform; guards are block-uniform (no divergence).
__global__ __launch_bounds__(256, 2)
void k_attn(const unsigned short* __restrict__ Qh, const unsigned short* __restrict__ Kh,
            const unsigned short* __restrict__ Vt, unsigned short* __restrict__ ctx) {
  __shared__ unsigned short Kl[2 * 4096];   // [buf][slot 64][hd 64], swizzled
  __shared__ unsigned short Vl[2 * 4096];   // [buf][hd 64][kv 64],  swizzled
  // decode: xcd = bid & 7 (1024 % 8 == 0, bijective)
  const int bid = blockIdx.x;
  const int g8  = bid & 7;                  // target XCD
  const int idx = bid >> 3;                 // 0..127
  const int bh  = g8 * 8 + (idx & 7);       // 8 heads per XCD
  const int jp  = idx >> 3;                 // pair index 0..15
  const int t = threadIdx.x, w = t >> 6, l = t & 63, lo = l & 15, hi = l >> 4;
  const unsigned short* Qb = Qh + (size_t)bh * S_ * HD_;
  const unsigned short* Kb = Kh + (size_t)bh * S_ * HD_;
  const unsigned short* Vb = Vt + (size_t)bh * S_ * HD_;   // [HD][S]
  const int bb = bh >> 4, h = bh & 15;

  // staging: 256 thr x 2 rows per matrix (rows t>>3 and +32), 16B chunks
  const int r0s = t >> 3, schunk = t & 7, r1s = r0s + 32;
  const int ks0 = ((r0s & 1) << 4) | ((r0s >> 1) & 15);            // r0s<32
  const int ks1 = 32 | ((r1s & 1) << 4) | ((r1s >> 1) & 15);
  const int kd0 = ks0 * 64 + 8 * (schunk ^ (ks0 & 7));
  const int kd1 = ks1 * 64 + 8 * (schunk ^ (ks1 & 7));
  const int vd0 = r0s * 64 + 8 * (schunk ^ (r0s & 7));
  const int vd1 = r1s * 64 + 8 * (schunk ^ (r1s & 7));
  const unsigned short* ksrc0 = Kb + r0s * HD_ + schunk * 8;          // + kv0*HD_
  const unsigned short* ksrc1 = Kb + r1s * HD_ + schunk * 8;
  const unsigned short* vsrc0 = Vb + (size_t)r0s * S_ + schunk * 8;   // + kv0
  const unsigned short* vsrc1 = Vb + (size_t)r1s * S_ + schunk * 8;

  const int e0 = jp + 1;                    // subtile-0 KV extent (tiles)
  const int nt = 32 - jp;                   // sweep length = subtile-1 extent

  s16x8 qf[2][2];
  int qbase[2];
  qbase[0] = 64 * jp        + w * 16;       // rows of subtile jp
  qbase[1] = 64 * (31 - jp) + w * 16;       // rows of subtile 31-jp
#pragma unroll
  for (int g = 0; g < 2; ++g)
#pragma unroll
    for (int kk = 0; kk < 2; ++kk)
      qf[g][kk] = *(const s16x8*)(Qb + (size_t)(qbase[g] + lo) * HD_ + kk * 32 + hi * 8);

  f32x4 O[2][4];
#pragma unroll
  for (int g = 0; g < 2; ++g)
#pragma unroll
    for (int nh = 0; nh < 4; ++nh) O[g][nh] = (f32x4){0.f, 0.f, 0.f, 0.f};
  float mrun[2] = {-1e30f, -1e30f}, lrun[2] = {0.f, 0.f};

  // prologue: tile 0 -> buf 0
  u16x8 rk0 = *(const u16x8*)ksrc0, rk1 = *(const u16x8*)ksrc1;
  u16x8 rv0 = *(const u16x8*)vsrc0, rv1 = *(const u16x8*)vsrc1;
  *(u16x8*)&Kl[kd0] = rk0;
  *(u16x8*)&Kl[kd1] = rk1;
  *(u16x8*)&Vl[vd0] = rv0;
  *(u16x8*)&Vl[vd1] = rv1;
  __syncthreads();

  for (int kt = 0; kt < nt; ++kt) {
    const int kv0 = kt * 64;
    const int cb = (kt & 1) * 4096;        // compute buffer
    const bool pf = (kt + 1 < nt);
    const bool g0act = (kt < e0);          // block-uniform
    if (pf) {                              // T14: issue loads BEFORE compute
      rk0 = *(const u16x8*)(ksrc0 + (size_t)(kv0 + 64) * HD_);
      rk1 = *(const u16x8*)(ksrc1 + (size_t)(kv0 + 64) * HD_);
      rv0 = *(const u16x8*)(vsrc0 + kv0 + 64);
      rv1 = *(const u16x8*)(vsrc1 + kv0 + 64);
    }

    // S^T = K Q^T : p[g][n][r] = S[kv0+32(n>>1)+8hi+2r+(n&1)][qbase[g]+lo]
    f32x4 p[2][4];
#pragma unroll
    for (int g = 0; g < 2; ++g)
#pragma unroll
      for (int n = 0; n < 4; ++n) p[g][n] = (f32x4){0.f, 0.f, 0.f, 0.f};
#pragma unroll
    for (int kk = 0; kk < 2; ++kk) {
      s16x8 kf[4];
#pragma unroll
      for (int n = 0; n < 4; ++n)
        kf[n] = *(const s16x8*)&Kl[cb + (n * 16 + lo) * 64 + 8 * ((kk * 4 + hi) ^ (lo & 7))];
      __builtin_amdgcn_s_setprio(1);
#pragma unroll
      for (int n = 0; n < 4; ++n)
        p[1][n] = __builtin_amdgcn_mfma_f32_16x16x32_bf16(kf[n], qf[1][kk], p[1][n], 0, 0, 0);
      if (g0act) {
#pragma unroll
        for (int n = 0; n < 4; ++n)
          p[0][n] = __builtin_amdgcn_mfma_f32_16x16x32_bf16(kf[n], qf[0][kk], p[0][n], 0, 0, 0);
      }
      __builtin_amdgcn_s_setprio(0);
    }

    union PU { unsigned int u[4]; s16x8 s; };
    PU pa[2][2];
#pragma unroll
    for (int g = 0; g < 2; ++g) {
      if (g == 0 && !g0act) continue;      // block-uniform skip
      if (kv0 + 63 > qbase[g]) {           // wave-uniform: mask only diagonal tiles
        const int q = qbase[g] + lo;
#pragma unroll
        for (int n = 0; n < 4; ++n)
#pragma unroll
          for (int r = 0; r < 4; ++r) {
            int kv = kv0 + 32 * (n >> 1) + 8 * hi + 2 * r + (n & 1);
            p[g][n][r] = (kv <= q) ? p[g][n][r] : -1e30f;
          }
      }
      // row max: 15 in-lane + xor16/32 across the q-column lane group
      float mx = fmaxf(fmaxf(fmaxf(p[g][0][0], p[g][0][1]), fmaxf(p[g][0][2], p[g][0][3])),
                       fmaxf(fmaxf(p[g][1][0], p[g][1][1]), fmaxf(p[g][1][2], p[g][1][3])));
      mx = fmaxf(mx, fmaxf(fmaxf(fmaxf(p[g][2][0], p[g][2][1]), fmaxf(p[g][2][2], p[g][2][3])),
                           fmaxf(fmaxf(p[g][3][0], p[g][3][1]), fmaxf(p[g][3][2], p[g][3][3]))));
      mx = fmaxf(mx, __shfl_xor(mx, 16));
      mx = fmaxf(mx, __shfl_xor(mx, 32));
      // T13 defer-max: only rescale when max grew past THR=8 (exp2 domain)
      const bool need = !__all(mx <= mrun[g] + 8.0f);
      if (need) {
        float mnew = fmaxf(mrun[g], mx);
        float alpha = exp2f(mrun[g] - mnew);
        mrun[g] = mnew;
        lrun[g] *= alpha;
#pragma unroll
        for (int r = 0; r < 4; ++r) {
          float ar_ = __shfl(alpha, 4 * hi + r);
#pragma unroll
          for (int nh = 0; nh < 4; ++nh) O[g][nh][r] *= ar_;
        }
      }
      float sum = 0.f;
#pragma unroll
      for (int n = 0; n < 4; ++n)
#pragma unroll
        for (int r = 0; r < 4; ++r) {
          float e = exp2f(p[g][n][r] - mrun[g]);   // masked: exp2(-1e30)=0
          p[g][n][r] = e;
          sum += e;
        }
      sum += __shfl_xor(sum, 16);
      sum += __shfl_xor(sum, 32);
      lrun[g] += sum;
      // pack P -> PV A-fragment: already lane-resident, just cvt_pk pairs
#pragma unroll
      for (int c = 0; c < 2; ++c)
#pragma unroll
        for (int r = 0; r < 4; ++r) {
          unsigned int pk;
          asm("v_cvt_pk_bf16_f32 %0, %1, %2"
              : "=v"(pk) : "v"(p[g][2 * c][r]), "v"(p[g][2 * c + 1][r]));
          pa[g][c].u[r] = pk;
        }
    }

    // O += P V
#pragma unroll
    for (int c = 0; c < 2; ++c) {
      s16x8 vf[4];
#pragma unroll
      for (int nh = 0; nh < 4; ++nh)
        vf[nh] = *(const s16x8*)&Vl[cb + (nh * 16 + lo) * 64 + 8 * ((4 * c + hi) ^ (lo & 7))];
      __builtin_amdgcn_s_setprio(1);
#pragma unroll
      for (int nh = 0; nh < 4; ++nh)
        O[1][nh] = __builtin_amdgcn_mfma_f32_16x16x32_bf16(pa[1][c].s, vf[nh], O[1][nh], 0, 0, 0);
      if (g0act) {
#pragma unroll
        for (int nh = 0; nh < 4; ++nh)
          O[0][nh] = __builtin_amdgcn_mfma_f32_16x16x32_bf16(pa[0][c].s, vf[nh], O[0][nh], 0, 0, 0);
      }
      __builtin_amdgcn_s_setprio(0);
    }

    if (pf) {                              // T14: write next tile AFTER compute
      const int db = ((kt + 1) & 1) * 4096;
      *(u16x8*)&Kl[db + kd0] = rk0;
      *(u16x8*)&Kl[db + kd1] = rk1;
      *(u16x8*)&Vl[db + vd0] = rv0;
      *(u16x8*)&Vl[db + vd1] = rv1;
      __syncthreads();                     // one barrier per tile
    }
  }

  // epilogue: ctx[B,S,H,HD] bf16
#pragma unroll
  for (int g = 0; g < 2; ++g) {
#pragma unroll
    for (int r = 0; r < 4; ++r) {
      float li = 1.0f / __shfl(lrun[g], 4 * hi + r);
      int qg = qbase[g] + 4 * hi + r;
#pragma unroll
      for (int nh = 0; nh < 4; ++nh) {
        int hd = nh * 16 + lo;
        ctx[(((size_t)(bb * S_ + qg)) * H_ + h) * HD_ + hd] = f2bf(O[g][nh][r] * li);
      }
    }
  }
}

// ---------------------------------------------------------------- launch
extern "C" void kernel_launch(void* const* d_in, const int* in_sizes, int n_in,
                              void* d_out, int out_size, void* d_ws, size_t ws_size,
                              hipStream_t stream) {
  const float* x      = (const float*)d_in[0];
  const float* W_attn = (const float*)d_in[1];
  const float* b_attn = (const float*)d_in[2];
  const float* W_proj = (const float*)d_in[3];
  const float* b_proj = (const float*)d_in[4];
  float* out = (float*)d_out;

  char* ws = (char*)d_ws;
  size_t off = 0;
  auto alloc = [&](size_t bytes) {
    char* p = ws + off;
    off += (bytes + 255) & ~(size_t)255;
    return p;
  };
  unsigned short* xb  = (unsigned short*)alloc((size_t)8192 * 1024 * 2);
  unsigned short* Wta = (unsigned short*)alloc((size_t)3072 * 1024 * 2);
  unsigned short* Wtp = (unsigned short*)alloc((size_t)1024 * 1024 * 2);
  unsigned short* Qh  = (unsigned short*)alloc((size_t)64 * 2048 * 64 * 2);
  unsigned short* Kh  = (unsigned short*)alloc((size_t)64 * 2048 * 64 * 2);
  unsigned short* Vh  = (unsigned short*)alloc((size_t)64 * 2048 * 64 * 2);
  unsigned short* Vt  = (unsigned short*)alloc((size_t)64 * 2048 * 64 * 2);
  unsigned short* ctx = (unsigned short*)alloc((size_t)8192 * 1024 * 2);

  k_cvt<<<dim3(2048), dim3(256), 0, stream>>>(x, xb, (8192 * 1024) / 4);
  k_tpose_cvt<<<dim3(48, 16), dim3(256), 0, stream>>>(W_attn, Wta, 1024, 3072);
  k_tpose_cvt<<<dim3(16, 16), dim3(256), 0, stream>>>(W_proj, Wtp, 1024, 1024);
  k_gemm_qkv<<<dim3(24, 64), dim3(256), 0, stream>>>(xb, Wta, b_attn, Qh, Kh, Vh);
  k_tpose_v<<<dim3(32, 64), dim3(256), 0, stream>>>(Vh, Vt);
  k_attn<<<dim3(1024), dim3(256), 0, stream>>>(Qh, Kh, Vt, ctx);
  k_gemm_proj<<<dim3(8, 64), dim3(256), 0, stream>>>(ctx, Wtp, b_proj, out, 1024);
}

// Round 9
// 194.401 us; speedup vs baseline: 1.0254x; 1.0254x over previous
//
#include <hip/hip_runtime.h>
#include <hip/hip_bf16.h>
#include <stdint.h>

// Problem constants: B=4, S=2048, D=1024, H=16, HD=64
#define B_  4
#define S_  2048
#define D_  1024
#define H_  16
#define HD_ 64

typedef __attribute__((ext_vector_type(8))) short          s16x8;   // MFMA A/B frag (8 bf16)
typedef __attribute__((ext_vector_type(4))) float          f32x4;   // MFMA C/D frag
typedef __attribute__((ext_vector_type(8))) unsigned short u16x8;   // 16B bf16 chunk

__device__ __forceinline__ unsigned short f2bf(float f) {
  union { float f; unsigned int u; } v; v.f = f;
  unsigned int u = v.u;
  u += 0x7fffu + ((u >> 16) & 1u);       // RNE
  return (unsigned short)(u >> 16);
}

// async global->LDS, 16B per lane; LDS dest = wave-uniform base + lane*16
#define GLDS16(g, l)                                                           \
  __builtin_amdgcn_global_load_lds(                                            \
      (const __attribute__((address_space(1))) void*)(g),                      \
      (__attribute__((address_space(3))) void*)(l), 16, 0, 0)

// ---------------------------------------------------------------- converts
__global__ void k_cvt(const float* __restrict__ src, unsigned short* __restrict__ dst, int n4) {
  int i = blockIdx.x * blockDim.x + threadIdx.x;
  int stride = gridDim.x * blockDim.x;
  for (int j = i; j < n4; j += stride) {
    float4 v = reinterpret_cast<const float4*>(src)[j];
    ushort4 o;
    o.x = f2bf(v.x); o.y = f2bf(v.y); o.z = f2bf(v.z); o.w = f2bf(v.w);
    reinterpret_cast<ushort4*>(dst)[j] = o;
  }
}

// fp32 [R][C] -> bf16 [C][R]   (weights -> B^T layout for gemm-BT)
__global__ void k_tpose_cvt(const float* __restrict__ src, unsigned short* __restrict__ dst,
                            int R, int C) {
  __shared__ unsigned short tile[64][72];
  int c0 = blockIdx.x * 64, r0 = blockIdx.y * 64;
  int tx = threadIdx.x & 63, ty = threadIdx.x >> 6;
#pragma unroll
  for (int i = 0; i < 16; ++i) {
    int r = ty * 16 + i;
    tile[r][tx] = f2bf(src[(size_t)(r0 + r) * C + c0 + tx]);
  }
  __syncthreads();
#pragma unroll
  for (int i = 0; i < 16; ++i) {
    int c = ty * 16 + i;
    dst[(size_t)(c0 + c) * R + r0 + tx] = tile[tx][c];
  }
}

// bf16 V [BH][S][HD] -> Vt [BH][HD][S]
__global__ void k_tpose_v(const unsigned short* __restrict__ src, unsigned short* __restrict__ dst) {
  __shared__ unsigned short tile[64][72];
  int s0 = blockIdx.x * 64, bh = blockIdx.y;
  int tx = threadIdx.x & 63, ty = threadIdx.x >> 6;
  const unsigned short* sb = src + (size_t)bh * S_ * HD_;
  unsigned short*       db = dst + (size_t)bh * S_ * HD_;
#pragma unroll
  for (int i = 0; i < 16; ++i) {
    int r = ty * 16 + i;
    tile[r][tx] = sb[(size_t)(s0 + r) * HD_ + tx];
  }
  __syncthreads();
#pragma unroll
  for (int i = 0; i < 16; ++i) {
    int hd = ty * 16 + i;
    db[(size_t)hd * S_ + s0 + tx] = tile[tx][hd];
  }
}

// ---------------------------------------------------------------- GEMM core
// (unchanged: global_load_lds width=16, linear LDS dest, source-side XOR
//  chunk swizzle, one barrier per K-step)
__device__ __forceinline__ void gemm_core(const unsigned short* __restrict__ A,
                                          const unsigned short* __restrict__ Bt,
                                          int K, int m0, int n0,
                                          unsigned short* sm, f32x4 acc[4][4]) {
  const int t = threadIdx.x;
  const int w = t >> 6, l = t & 63;
  const int wm = w >> 1, wn = w & 1;
  const int lo = l & 15, hi = l >> 4;

  const int ci0 = w * 64 + l, ci1 = ci0 + 256;
  const int rA0 = ci0 >> 2, cA0 = (ci0 & 3) ^ ((rA0 >> 1) & 3);
  const int rA1 = ci1 >> 2, cA1 = (ci1 & 3) ^ ((rA1 >> 1) & 3);
  const unsigned short* gA0 = A  + (size_t)(m0 + rA0) * K + cA0 * 8;
  const unsigned short* gA1 = A  + (size_t)(m0 + rA1) * K + cA1 * 8;
  const unsigned short* gB0 = Bt + (size_t)(n0 + rA0) * K + cA0 * 8;
  const unsigned short* gB1 = Bt + (size_t)(n0 + rA1) * K + cA1 * 8;
  const int ldsA0 = (w * 64) * 8;
  const int ldsA1 = (256 + w * 64) * 8;

#pragma unroll
  for (int m = 0; m < 4; ++m)
#pragma unroll
    for (int n = 0; n < 4; ++n)
      acc[m][n] = (f32x4){0.f, 0.f, 0.f, 0.f};

  const int NT = K >> 5;  // BK = 32

  {
    unsigned short* b = sm;
    GLDS16(gA0, b + ldsA0);
    GLDS16(gA1, b + ldsA1);
    GLDS16(gB0, b + 4096 + ldsA0);
    GLDS16(gB1, b + 4096 + ldsA1);
  }

  for (int kt = 0; kt < NT; ++kt) {
    __syncthreads();
    if (kt + 1 < NT) {
      unsigned short* b = sm + ((kt + 1) & 1) * 8192;
      const int ko = (kt + 1) << 5;
      GLDS16(gA0 + ko, b + ldsA0);
      GLDS16(gA1 + ko, b + ldsA1);
      GLDS16(gB0 + ko, b + 4096 + ldsA0);
      GLDS16(gB1 + ko, b + 4096 + ldsA1);
    }
    const unsigned short* Ab = sm + (kt & 1) * 8192;
    const unsigned short* Bb = Ab + 4096;
    s16x8 af[4], bfr[4];
#pragma unroll
    for (int m = 0; m < 4; ++m) {
      int row = wm * 64 + m * 16 + lo;
      af[m] = *(const s16x8*)(Ab + row * 32 + ((hi ^ ((row >> 1) & 3)) << 3));
    }
#pragma unroll
    for (int n = 0; n < 4; ++n) {
      int row = wn * 64 + n * 16 + lo;
      bfr[n] = *(const s16x8*)(Bb + row * 32 + ((hi ^ ((row >> 1) & 3)) << 3));
    }
    __builtin_amdgcn_s_setprio(1);
#pragma unroll
    for (int m = 0; m < 4; ++m)
#pragma unroll
      for (int n = 0; n < 4; ++n)
        acc[m][n] = __builtin_amdgcn_mfma_f32_16x16x32_bf16(af[m], bfr[n], acc[m][n], 0, 0, 0);
    __builtin_amdgcn_s_setprio(0);
  }
}

// GEMM1: qkv = x @ W_attn + b ; scatter into Q/K/V [B,H,S,HD] bf16.
__global__ __launch_bounds__(256, 3)
void k_gemm_qkv(const unsigned short* __restrict__ A, const unsigned short* __restrict__ Bt,
                const float* __restrict__ bias,
                unsigned short* __restrict__ Qh, unsigned short* __restrict__ Kh,
                unsigned short* __restrict__ Vh) {
  __shared__ unsigned short sm[2 * 8192];
  const int m0 = blockIdx.y * 128, n0 = blockIdx.x * 128;
  f32x4 acc[4][4];
  gemm_core(A, Bt, 1024, m0, n0, sm, acc);
  const int t = threadIdx.x, w = t >> 6, l = t & 63;
  const int wm = w >> 1, wn = w & 1, lo = l & 15, hi = l >> 4;
#pragma unroll
  for (int m = 0; m < 4; ++m)
#pragma unroll
    for (int n = 0; n < 4; ++n) {
      int col = n0 + wn * 64 + n * 16 + lo;           // 0..3071
      float bv = bias[col];
      int sel = col >> 10, cw = col & 1023, h = cw >> 6, hd = cw & 63;
      float scl = (sel == 0) ? 0.18033688011112042f : 1.0f;  // log2(e)/8
      unsigned short* dst = (sel == 0) ? Qh : ((sel == 1) ? Kh : Vh);
#pragma unroll
      for (int r = 0; r < 4; ++r) {
        int row = m0 + wm * 64 + m * 16 + hi * 4 + r;
        int b = row >> 11, s = row & 2047;
        dst[(((size_t)b * H_ + h) * S_ + s) * HD_ + hd] = f2bf((acc[m][n][r] + bv) * scl);
      }
    }
}

// GEMM2: out = ctx @ W_proj + b ; fp32 out
__global__ __launch_bounds__(256, 3)
void k_gemm_proj(const unsigned short* __restrict__ A, const unsigned short* __restrict__ Bt,
                 const float* __restrict__ bias, float* __restrict__ C, int N) {
  __shared__ unsigned short sm[2 * 8192];
  const int m0 = blockIdx.y * 128, n0 = blockIdx.x * 128;
  f32x4 acc[4][4];
  gemm_core(A, Bt, 1024, m0, n0, sm, acc);
  const int t = threadIdx.x, w = t >> 6, l = t & 63;
  const int wm = w >> 1, wn = w & 1, lo = l & 15, hi = l >> 4;
#pragma unroll
  for (int m = 0; m < 4; ++m)
#pragma unroll
    for (int n = 0; n < 4; ++n) {
      int col = n0 + wn * 64 + n * 16 + lo;
      float bv = bias[col];
#pragma unroll
      for (int r = 0; r < 4; ++r) {
        int row = m0 + wm * 64 + m * 16 + hi * 4 + r;
        C[(size_t)row * N + col] = acc[m][n][r] + bv;
      }
    }
}

// ---------------------------------------------------------------- attention
// Swapped QK^T (mfma(K,Q)); K rows LDS-permuted so the PV A-fragment is
// lane-resident after cvt_pk; G4 XOR chunk swizzle on K/V (0 conflicts);
// T13 defer-max; XCD swizzle; (jp, 31-jp) pairing.
// Round-9: KVBLK=128. Rounds 3/7/8 measured per-TILE-VISIT wall time
// ~2.6-3.1 us regardless of barriers (1 vs 2), g-work (1 vs 2), blocks/CU
// (2 vs 4) -> duration = max visits x ~3 us. So: halve the visit count.
// Each visit stages TWO 64-kv sub-tiles (same swizzle per sub-buffer; the
// verified 64-kv body runs twice with kv0/sub-offset parameters). Single
// 32KB buffer (same LDS -> same residency), T14 prefetch in 8 regs,
// barrier pair around the ds_write. Max visits 32 -> 16.
__global__ __launch_bounds__(256, 2)
void k_attn(const unsigned short* __restrict__ Qh, const unsigned short* __restrict__ Kh,
            const unsigned short* __restrict__ Vt, unsigned short* __restrict__ ctx) {
  __shared__ unsigned short Kl[2 * 4096];   // [sub][slot 64][hd 64], swizzled
  __shared__ unsigned short Vl[2 * 4096];   // [sub][hd 64][kv 64],  swizzled
  // decode: xcd = bid & 7 (1024 % 8 == 0, bijective)
  const int bid = blockIdx.x;
  const int g8  = bid & 7;                  // target XCD
  const int idx = bid >> 3;                 // 0..127
  const int bh  = g8 * 8 + (idx & 7);       // 8 heads per XCD
  const int jp  = idx >> 3;                 // pair index 0..15
  const int t = threadIdx.x, w = t >> 6, l = t & 63, lo = l & 15, hi = l >> 4;
  const unsigned short* Qb = Qh + (size_t)bh * S_ * HD_;
  const unsigned short* Kb = Kh + (size_t)bh * S_ * HD_;
  const unsigned short* Vb = Vt + (size_t)bh * S_ * HD_;   // [HD][S]
  const int bb = bh >> 4, h = bh & 15;

  // staging: per sub-tile, thread handles rows t>>3 and +32, 16B chunks
  const int r0s = t >> 3, schunk = t & 7, r1s = r0s + 32;
  const int ks0 = ((r0s & 1) << 4) | ((r0s >> 1) & 15);            // r0s<32
  const int ks1 = 32 | ((r1s & 1) << 4) | ((r1s >> 1) & 15);
  const int kd0 = ks0 * 64 + 8 * (schunk ^ (ks0 & 7));
  const int kd1 = ks1 * 64 + 8 * (schunk ^ (ks1 & 7));
  const int vd0 = r0s * 64 + 8 * (schunk ^ (r0s & 7));
  const int vd1 = r1s * 64 + 8 * (schunk ^ (r1s & 7));
  const unsigned short* ksrc0 = Kb + r0s * HD_ + schunk * 8;          // + kv*HD_
  const unsigned short* ksrc1 = Kb + r1s * HD_ + schunk * 8;
  const unsigned short* vsrc0 = Vb + (size_t)r0s * S_ + schunk * 8;   // + kv
  const unsigned short* vsrc1 = Vb + (size_t)r1s * S_ + schunk * 8;

  const int e0  = jp + 1;                   // subtile-0 extent (64-tiles)
  const int ex1 = 32 - jp;                  // subtile-1 extent (64-tiles)
  const int nv  = (ex1 + 1) >> 1;           // 128-kv visits: 9..16

  s16x8 qf[2][2];
  int qbase[2];
  qbase[0] = 64 * jp        + w * 16;
  qbase[1] = 64 * (31 - jp) + w * 16;
#pragma unroll
  for (int g = 0; g < 2; ++g)
#pragma unroll
    for (int kk = 0; kk < 2; ++kk)
      qf[g][kk] = *(const s16x8*)(Qb + (size_t)(qbase[g] + lo) * HD_ + kk * 32 + hi * 8);

  f32x4 O[2][4];
#pragma unroll
  for (int g = 0; g < 2; ++g)
#pragma unroll
    for (int nh = 0; nh < 4; ++nh) O[g][nh] = (f32x4){0.f, 0.f, 0.f, 0.f};
  float mrun[2] = {-1e30f, -1e30f}, lrun[2] = {0.f, 0.f};

  // verified 64-kv body (round-3..8 inner math, byte-identical):
  auto process = [&](int kv0, int sub, bool g0act) {
    const unsigned short* Kbuf = Kl + sub * 4096;
    const unsigned short* Vbuf = Vl + sub * 4096;
    f32x4 p[2][4];
#pragma unroll
    for (int g = 0; g < 2; ++g)
#pragma unroll
      for (int n = 0; n < 4; ++n) p[g][n] = (f32x4){0.f, 0.f, 0.f, 0.f};
#pragma unroll
    for (int kk = 0; kk < 2; ++kk) {
      s16x8 kf[4];
#pragma unroll
      for (int n = 0; n < 4; ++n)
        kf[n] = *(const s16x8*)&Kbuf[(n * 16 + lo) * 64 + 8 * ((kk * 4 + hi) ^ (lo & 7))];
      __builtin_amdgcn_s_setprio(1);
#pragma unroll
      for (int n = 0; n < 4; ++n)
        p[1][n] = __builtin_amdgcn_mfma_f32_16x16x32_bf16(kf[n], qf[1][kk], p[1][n], 0, 0, 0);
      if (g0act) {
#pragma unroll
        for (int n = 0; n < 4; ++n)
          p[0][n] = __builtin_amdgcn_mfma_f32_16x16x32_bf16(kf[n], qf[0][kk], p[0][n], 0, 0, 0);
      }
      __builtin_amdgcn_s_setprio(0);
    }

    union PU { unsigned int u[4]; s16x8 s; };
    PU pa[2][2];
#pragma unroll
    for (int g = 0; g < 2; ++g) {
      if (g == 0 && !g0act) continue;      // block-uniform skip
      if (kv0 + 63 > qbase[g]) {           // wave-uniform: diagonal tile only
        const int q = qbase[g] + lo;
#pragma unroll
        for (int n = 0; n < 4; ++n)
#pragma unroll
          for (int r = 0; r < 4; ++r) {
            int kv = kv0 + 32 * (n >> 1) + 8 * hi + 2 * r + (n & 1);
            p[g][n][r] = (kv <= q) ? p[g][n][r] : -1e30f;
          }
      }
      float mx = fmaxf(fmaxf(fmaxf(p[g][0][0], p[g][0][1]), fmaxf(p[g][0][2], p[g][0][3])),
                       fmaxf(fmaxf(p[g][1][0], p[g][1][1]), fmaxf(p[g][1][2], p[g][1][3])));
      mx = fmaxf(mx, fmaxf(fmaxf(fmaxf(p[g][2][0], p[g][2][1]), fmaxf(p[g][2][2], p[g][2][3])),
                           fmaxf(fmaxf(p[g][3][0], p[g][3][1]), fmaxf(p[g][3][2], p[g][3][3]))));
      mx = fmaxf(mx, __shfl_xor(mx, 16));
      mx = fmaxf(mx, __shfl_xor(mx, 32));
      const bool need = !__all(mx <= mrun[g] + 8.0f);    // T13 defer-max
      if (need) {
        float mnew = fmaxf(mrun[g], mx);
        float alpha = exp2f(mrun[g] - mnew);
        mrun[g] = mnew;
        lrun[g] *= alpha;
#pragma unroll
        for (int r = 0; r < 4; ++r) {
          float ar_ = __shfl(alpha, 4 * hi + r);
#pragma unroll
          for (int nh = 0; nh < 4; ++nh) O[g][nh][r] *= ar_;
        }
      }
      float sum = 0.f;
#pragma unroll
      for (int n = 0; n < 4; ++n)
#pragma unroll
        for (int r = 0; r < 4; ++r) {
          float e = exp2f(p[g][n][r] - mrun[g]);   // masked: exp2(-1e30)=0
          p[g][n][r] = e;
          sum += e;
        }
      sum += __shfl_xor(sum, 16);
      sum += __shfl_xor(sum, 32);
      lrun[g] += sum;
#pragma unroll
      for (int c = 0; c < 2; ++c)
#pragma unroll
        for (int r = 0; r < 4; ++r) {
          unsigned int pk;
          asm("v_cvt_pk_bf16_f32 %0, %1, %2"
              : "=v"(pk) : "v"(p[g][2 * c][r]), "v"(p[g][2 * c + 1][r]));
          pa[g][c].u[r] = pk;
        }
    }

#pragma unroll
    for (int c = 0; c < 2; ++c) {
      s16x8 vf[4];
#pragma unroll
      for (int nh = 0; nh < 4; ++nh)
        vf[nh] = *(const s16x8*)&Vbuf[(nh * 16 + lo) * 64 + 8 * ((4 * c + hi) ^ (lo & 7))];
      __builtin_amdgcn_s_setprio(1);
#pragma unroll
      for (int nh = 0; nh < 4; ++nh)
        O[1][nh] = __builtin_amdgcn_mfma_f32_16x16x32_bf16(pa[1][c].s, vf[nh], O[1][nh], 0, 0, 0);
      if (g0act) {
#pragma unroll
        for (int nh = 0; nh < 4; ++nh)
          O[0][nh] = __builtin_amdgcn_mfma_f32_16x16x32_bf16(pa[0][c].s, vf[nh], O[0][nh], 0, 0, 0);
      }
      __builtin_amdgcn_s_setprio(0);
    }
  };

  // prologue: visit 0 (tiles 0,1) -> LDS
  u16x8 rk00 = *(const u16x8*)ksrc0;
  u16x8 rk01 = *(const u16x8*)ksrc1;
  u16x8 rk10 = *(const u16x8*)(ksrc0 + (size_t)64 * HD_);
  u16x8 rk11 = *(const u16x8*)(ksrc1 + (size_t)64 * HD_);
  u16x8 rv00 = *(const u16x8*)vsrc0;
  u16x8 rv01 = *(const u16x8*)vsrc1;
  u16x8 rv10 = *(const u16x8*)(vsrc0 + 64);
  u16x8 rv11 = *(const u16x8*)(vsrc1 + 64);
  *(u16x8*)&Kl[kd0] = rk00;        *(u16x8*)&Kl[kd1] = rk01;
  *(u16x8*)&Kl[4096 + kd0] = rk10; *(u16x8*)&Kl[4096 + kd1] = rk11;
  *(u16x8*)&Vl[vd0] = rv00;        *(u16x8*)&Vl[vd1] = rv01;
  *(u16x8*)&Vl[4096 + vd0] = rv10; *(u16x8*)&Vl[4096 + vd1] = rv11;
  __syncthreads();

  for (int kt = 0; kt < nv; ++kt) {
    const int base = kt * 128;
    const bool pf = (kt + 1 < nv);
    if (pf) {                              // T14: issue loads BEFORE compute
      const int nb = base + 128;
      rk00 = *(const u16x8*)(ksrc0 + (size_t)nb * HD_);
      rk01 = *(const u16x8*)(ksrc1 + (size_t)nb * HD_);
      rk10 = *(const u16x8*)(ksrc0 + (size_t)(nb + 64) * HD_);
      rk11 = *(const u16x8*)(ksrc1 + (size_t)(nb + 64) * HD_);
      rv00 = *(const u16x8*)(vsrc0 + nb);
      rv01 = *(const u16x8*)(vsrc1 + nb);
      rv10 = *(const u16x8*)(vsrc0 + nb + 64);
      rv11 = *(const u16x8*)(vsrc1 + nb + 64);
    }

    process(base, 0, 2 * kt < e0);              // sub-tile 0 (always < ex1)
    if (2 * kt + 1 < ex1)
      process(base + 64, 1, 2 * kt + 1 < e0);   // sub-tile 1

    if (pf) {                              // T14: write AFTER compute
      __syncthreads();                     // all reads of Kl/Vl done
      *(u16x8*)&Kl[kd0] = rk00;        *(u16x8*)&Kl[kd1] = rk01;
      *(u16x8*)&Kl[4096 + kd0] = rk10; *(u16x8*)&Kl[4096 + kd1] = rk11;
      *(u16x8*)&Vl[vd0] = rv00;        *(u16x8*)&Vl[vd1] = rv01;
      *(u16x8*)&Vl[4096 + vd0] = rv10; *(u16x8*)&Vl[4096 + vd1] = rv11;
      __syncthreads();                     // staged visible
    }
  }

  // epilogue: ctx[B,S,H,HD] bf16
#pragma unroll
  for (int g = 0; g < 2; ++g) {
#pragma unroll
    for (int r = 0; r < 4; ++r) {
      float li = 1.0f / __shfl(lrun[g], 4 * hi + r);
      int qg = qbase[g] + 4 * hi + r;
#pragma unroll
      for (int nh = 0; nh < 4; ++nh) {
        int hd = nh * 16 + lo;
        ctx[(((size_t)(bb * S_ + qg)) * H_ + h) * HD_ + hd] = f2bf(O[g][nh][r] * li);
      }
    }
  }
}

// ---------------------------------------------------------------- launch
extern "C" void kernel_launch(void* const* d_in, const int* in_sizes, int n_in,
                              void* d_out, int out_size, void* d_ws, size_t ws_size,
                              hipStream_t stream) {
  const float* x      = (const float*)d_in[0];
  const float* W_attn = (const float*)d_in[1];
  const float* b_attn = (const float*)d_in[2];
  const float* W_proj = (const float*)d_in[3];
  const float* b_proj = (const float*)d_in[4];
  float* out = (float*)d_out;

  char* ws = (char*)d_ws;
  size_t off = 0;
  auto alloc = [&](size_t bytes) {
    char* p = ws + off;
    off += (bytes + 255) & ~(size_t)255;
    return p;
  };
  unsigned short* xb  = (unsigned short*)alloc((size_t)8192 * 1024 * 2);
  unsigned short* Wta = (unsigned short*)alloc((size_t)3072 * 1024 * 2);
  unsigned short* Wtp = (unsigned short*)alloc((size_t)1024 * 1024 * 2);
  unsigned short* Qh  = (unsigned short*)alloc((size_t)64 * 2048 * 64 * 2);
  unsigned short* Kh  = (unsigned short*)alloc((size_t)64 * 2048 * 64 * 2);
  unsigned short* Vh  = (unsigned short*)alloc((size_t)64 * 2048 * 64 * 2);
  unsigned short* Vt  = (unsigned short*)alloc((size_t)64 * 2048 * 64 * 2);
  unsigned short* ctx = (unsigned short*)alloc((size_t)8192 * 1024 * 2);

  k_cvt<<<dim3(2048), dim3(256), 0, stream>>>(x, xb, (8192 * 1024) / 4);
  k_tpose_cvt<<<dim3(48, 16), dim3(256), 0, stream>>>(W_attn, Wta, 1024, 3072);
  k_tpose_cvt<<<dim3(16, 16), dim3(256), 0, stream>>>(W_proj, Wtp, 1024, 1024);
  k_gemm_qkv<<<dim3(24, 64), dim3(256), 0, stream>>>(xb, Wta, b_attn, Qh, Kh, Vh);
  k_tpose_v<<<dim3(32, 64), dim3(256), 0, stream>>>(Vh, Vt);
  k_attn<<<dim3(1024), dim3(256), 0, stream>>>(Qh, Kh, Vt, ctx);
  k_gemm_proj<<<dim3(8, 64), dim3(256), 0, stream>>>(ctx, Wtp, b_proj, out, 1024);
}

// Round 10
// 182.149 us; speedup vs baseline: 1.0944x; 1.0673x over previous
//
#include <hip/hip_runtime.h>
#include <hip/hip_bf16.h>
#include <stdint.h>

// Problem constants: B=4, S=2048, D=1024, H=16, HD=64
#define B_  4
#define S_  2048
#define D_  1024
#define H_  16
#define HD_ 64

typedef __attribute__((ext_vector_type(8))) short          s16x8;   // MFMA A/B frag (8 bf16)
typedef __attribute__((ext_vector_type(4))) float          f32x4;   // MFMA C/D frag
typedef __attribute__((ext_vector_type(8))) unsigned short u16x8;   // 16B bf16 chunk

__device__ __forceinline__ unsigned short f2bf(float f) {
  union { float f; unsigned int u; } v; v.f = f;
  unsigned int u = v.u;
  u += 0x7fffu + ((u >> 16) & 1u);       // RNE
  return (unsigned short)(u >> 16);
}

// async global->LDS, 16B per lane; LDS dest = wave-uniform base + lane*16
#define GLDS16(g, l)                                                           \
  __builtin_amdgcn_global_load_lds(                                            \
      (const __attribute__((address_space(1))) void*)(g),                      \
      (__attribute__((address_space(3))) void*)(l), 16, 0, 0)

// ---------------------------------------------------------------- converts
__global__ void k_cvt(const float* __restrict__ src, unsigned short* __restrict__ dst, int n4) {
  int i = blockIdx.x * blockDim.x + threadIdx.x;
  int stride = gridDim.x * blockDim.x;
  for (int j = i; j < n4; j += stride) {
    float4 v = reinterpret_cast<const float4*>(src)[j];
    ushort4 o;
    o.x = f2bf(v.x); o.y = f2bf(v.y); o.z = f2bf(v.z); o.w = f2bf(v.w);
    reinterpret_cast<ushort4*>(dst)[j] = o;
  }
}

// fp32 [R][C] -> bf16 [C][R]   (weights -> B^T layout for gemm-BT)
__global__ void k_tpose_cvt(const float* __restrict__ src, unsigned short* __restrict__ dst,
                            int R, int C) {
  __shared__ unsigned short tile[64][72];
  int c0 = blockIdx.x * 64, r0 = blockIdx.y * 64;
  int tx = threadIdx.x & 63, ty = threadIdx.x >> 6;
#pragma unroll
  for (int i = 0; i < 16; ++i) {
    int r = ty * 16 + i;
    tile[r][tx] = f2bf(src[(size_t)(r0 + r) * C + c0 + tx]);
  }
  __syncthreads();
#pragma unroll
  for (int i = 0; i < 16; ++i) {
    int c = ty * 16 + i;
    dst[(size_t)(c0 + c) * R + r0 + tx] = tile[tx][c];
  }
}

// bf16 V [BH][S][HD] -> Vt [BH][HD][S]
__global__ void k_tpose_v(const unsigned short* __restrict__ src, unsigned short* __restrict__ dst) {
  __shared__ unsigned short tile[64][72];
  int s0 = blockIdx.x * 64, bh = blockIdx.y;
  int tx = threadIdx.x & 63, ty = threadIdx.x >> 6;
  const unsigned short* sb = src + (size_t)bh * S_ * HD_;
  unsigned short*       db = dst + (size_t)bh * S_ * HD_;
#pragma unroll
  for (int i = 0; i < 16; ++i) {
    int r = ty * 16 + i;
    tile[r][tx] = sb[(size_t)(s0 + r) * HD_ + tx];
  }
  __syncthreads();
#pragma unroll
  for (int i = 0; i < 16; ++i) {
    int hd = ty * 16 + i;
    db[(size_t)hd * S_ + s0 + tx] = tile[tx][hd];
  }
}

// ---------------------------------------------------------------- GEMM core
// (unchanged: global_load_lds width=16, linear LDS dest, source-side XOR
//  chunk swizzle, one barrier per K-step)
__device__ __forceinline__ void gemm_core(const unsigned short* __restrict__ A,
                                          const unsigned short* __restrict__ Bt,
                                          int K, int m0, int n0,
                                          unsigned short* sm, f32x4 acc[4][4]) {
  const int t = threadIdx.x;
  const int w = t >> 6, l = t & 63;
  const int wm = w >> 1, wn = w & 1;
  const int lo = l & 15, hi = l >> 4;

  const int ci0 = w * 64 + l, ci1 = ci0 + 256;
  const int rA0 = ci0 >> 2, cA0 = (ci0 & 3) ^ ((rA0 >> 1) & 3);
  const int rA1 = ci1 >> 2, cA1 = (ci1 & 3) ^ ((rA1 >> 1) & 3);
  const unsigned short* gA0 = A  + (size_t)(m0 + rA0) * K + cA0 * 8;
  const unsigned short* gA1 = A  + (size_t)(m0 + rA1) * K + cA1 * 8;
  const unsigned short* gB0 = Bt + (size_t)(n0 + rA0) * K + cA0 * 8;
  const unsigned short* gB1 = Bt + (size_t)(n0 + rA1) * K + cA1 * 8;
  const int ldsA0 = (w * 64) * 8;
  const int ldsA1 = (256 + w * 64) * 8;

#pragma unroll
  for (int m = 0; m < 4; ++m)
#pragma unroll
    for (int n = 0; n < 4; ++n)
      acc[m][n] = (f32x4){0.f, 0.f, 0.f, 0.f};

  const int NT = K >> 5;  // BK = 32

  {
    unsigned short* b = sm;
    GLDS16(gA0, b + ldsA0);
    GLDS16(gA1, b + ldsA1);
    GLDS16(gB0, b + 4096 + ldsA0);
    GLDS16(gB1, b + 4096 + ldsA1);
  }

  for (int kt = 0; kt < NT; ++kt) {
    __syncthreads();
    if (kt + 1 < NT) {
      unsigned short* b = sm + ((kt + 1) & 1) * 8192;
      const int ko = (kt + 1) << 5;
      GLDS16(gA0 + ko, b + ldsA0);
      GLDS16(gA1 + ko, b + ldsA1);
      GLDS16(gB0 + ko, b + 4096 + ldsA0);
      GLDS16(gB1 + ko, b + 4096 + ldsA1);
    }
    const unsigned short* Ab = sm + (kt & 1) * 8192;
    const unsigned short* Bb = Ab + 4096;
    s16x8 af[4], bfr[4];
#pragma unroll
    for (int m = 0; m < 4; ++m) {
      int row = wm * 64 + m * 16 + lo;
      af[m] = *(const s16x8*)(Ab + row * 32 + ((hi ^ ((row >> 1) & 3)) << 3));
    }
#pragma unroll
    for (int n = 0; n < 4; ++n) {
      int row = wn * 64 + n * 16 + lo;
      bfr[n] = *(const s16x8*)(Bb + row * 32 + ((hi ^ ((row >> 1) & 3)) << 3));
    }
    __builtin_amdgcn_s_setprio(1);
#pragma unroll
    for (int m = 0; m < 4; ++m)
#pragma unroll
      for (int n = 0; n < 4; ++n)
        acc[m][n] = __builtin_amdgcn_mfma_f32_16x16x32_bf16(af[m], bfr[n], acc[m][n], 0, 0, 0);
    __builtin_amdgcn_s_setprio(0);
  }
}

// GEMM1: qkv = x @ W_attn + b ; scatter into Q/K/V [B,H,S,HD] bf16.
__global__ __launch_bounds__(256, 3)
void k_gemm_qkv(const unsigned short* __restrict__ A, const unsigned short* __restrict__ Bt,
                const float* __restrict__ bias,
                unsigned short* __restrict__ Qh, unsigned short* __restrict__ Kh,
                unsigned short* __restrict__ Vh) {
  __shared__ unsigned short sm[2 * 8192];
  const int m0 = blockIdx.y * 128, n0 = blockIdx.x * 128;
  f32x4 acc[4][4];
  gemm_core(A, Bt, 1024, m0, n0, sm, acc);
  const int t = threadIdx.x, w = t >> 6, l = t & 63;
  const int wm = w >> 1, wn = w & 1, lo = l & 15, hi = l >> 4;
#pragma unroll
  for (int m = 0; m < 4; ++m)
#pragma unroll
    for (int n = 0; n < 4; ++n) {
      int col = n0 + wn * 64 + n * 16 + lo;           // 0..3071
      float bv = bias[col];
      int sel = col >> 10, cw = col & 1023, h = cw >> 6, hd = cw & 63;
      float scl = (sel == 0) ? 0.18033688011112042f : 1.0f;  // log2(e)/8
      unsigned short* dst = (sel == 0) ? Qh : ((sel == 1) ? Kh : Vh);
#pragma unroll
      for (int r = 0; r < 4; ++r) {
        int row = m0 + wm * 64 + m * 16 + hi * 4 + r;
        int b = row >> 11, s = row & 2047;
        dst[(((size_t)b * H_ + h) * S_ + s) * HD_ + hd] = f2bf((acc[m][n][r] + bv) * scl);
      }
    }
}

// GEMM2: out = ctx @ W_proj + b ; fp32 out
__global__ __launch_bounds__(256, 3)
void k_gemm_proj(const unsigned short* __restrict__ A, const unsigned short* __restrict__ Bt,
                 const float* __restrict__ bias, float* __restrict__ C, int N) {
  __shared__ unsigned short sm[2 * 8192];
  const int m0 = blockIdx.y * 128, n0 = blockIdx.x * 128;
  f32x4 acc[4][4];
  gemm_core(A, Bt, 1024, m0, n0, sm, acc);
  const int t = threadIdx.x, w = t >> 6, l = t & 63;
  const int wm = w >> 1, wn = w & 1, lo = l & 15, hi = l >> 4;
#pragma unroll
  for (int m = 0; m < 4; ++m)
#pragma unroll
    for (int n = 0; n < 4; ++n) {
      int col = n0 + wn * 64 + n * 16 + lo;
      float bv = bias[col];
#pragma unroll
      for (int r = 0; r < 4; ++r) {
        int row = m0 + wm * 64 + m * 16 + hi * 4 + r;
        C[(size_t)row * N + col] = acc[m][n][r] + bv;
      }
    }
}

// ---------------------------------------------------------------- attention
// Swapped QK^T (mfma(K,Q)); K rows LDS-permuted so the PV A-fragment is
// lane-resident after cvt_pk; G4 XOR chunk swizzle on K/V (0 conflicts);
// XCD swizzle; (jp, 31-jp) pairing; KVBLK=128 staging.
// Round-10: LANE-LOCAL SOFTMAX. Rounds 3/7/8/9 measured ~3us per 64-kv
// process call (invariant across barriers/visits/occupancy) -> call is
// dependency-latency-bound; the 4-6 cross-lane shfl ops (60cyc each) were
// the fixed links. Now the common path has ZERO cross-lane ops:
//  - defer-max check via __all(lane_mx <= mrun+8) (no max shfl; full row
//    max computed only in the rare rescale branch)
//  - lrun is a PER-LANE PARTIAL sum (no sum shfl per call); the 16/32
//    shfl_xor reduction runs once in the epilogue. Rescale multiplies the
//    partial by the row-consistent alpha, keeping partials coherent.
__global__ __launch_bounds__(256, 2)
void k_attn(const unsigned short* __restrict__ Qh, const unsigned short* __restrict__ Kh,
            const unsigned short* __restrict__ Vt, unsigned short* __restrict__ ctx) {
  __shared__ unsigned short Kl[2 * 4096];   // [sub][slot 64][hd 64], swizzled
  __shared__ unsigned short Vl[2 * 4096];   // [sub][hd 64][kv 64],  swizzled
  // decode: xcd = bid & 7 (1024 % 8 == 0, bijective)
  const int bid = blockIdx.x;
  const int g8  = bid & 7;                  // target XCD
  const int idx = bid >> 3;                 // 0..127
  const int bh  = g8 * 8 + (idx & 7);       // 8 heads per XCD
  const int jp  = idx >> 3;                 // pair index 0..15
  const int t = threadIdx.x, w = t >> 6, l = t & 63, lo = l & 15, hi = l >> 4;
  const unsigned short* Qb = Qh + (size_t)bh * S_ * HD_;
  const unsigned short* Kb = Kh + (size_t)bh * S_ * HD_;
  const unsigned short* Vb = Vt + (size_t)bh * S_ * HD_;   // [HD][S]
  const int bb = bh >> 4, h = bh & 15;

  // staging: per sub-tile, thread handles rows t>>3 and +32, 16B chunks
  const int r0s = t >> 3, schunk = t & 7, r1s = r0s + 32;
  const int ks0 = ((r0s & 1) << 4) | ((r0s >> 1) & 15);            // r0s<32
  const int ks1 = 32 | ((r1s & 1) << 4) | ((r1s >> 1) & 15);
  const int kd0 = ks0 * 64 + 8 * (schunk ^ (ks0 & 7));
  const int kd1 = ks1 * 64 + 8 * (schunk ^ (ks1 & 7));
  const int vd0 = r0s * 64 + 8 * (schunk ^ (r0s & 7));
  const int vd1 = r1s * 64 + 8 * (schunk ^ (r1s & 7));
  const unsigned short* ksrc0 = Kb + r0s * HD_ + schunk * 8;          // + kv*HD_
  const unsigned short* ksrc1 = Kb + r1s * HD_ + schunk * 8;
  const unsigned short* vsrc0 = Vb + (size_t)r0s * S_ + schunk * 8;   // + kv
  const unsigned short* vsrc1 = Vb + (size_t)r1s * S_ + schunk * 8;

  const int e0  = jp + 1;                   // subtile-0 extent (64-tiles)
  const int ex1 = 32 - jp;                  // subtile-1 extent (64-tiles)
  const int nv  = (ex1 + 1) >> 1;           // 128-kv visits: 9..16

  s16x8 qf[2][2];
  int qbase[2];
  qbase[0] = 64 * jp        + w * 16;
  qbase[1] = 64 * (31 - jp) + w * 16;
#pragma unroll
  for (int g = 0; g < 2; ++g)
#pragma unroll
    for (int kk = 0; kk < 2; ++kk)
      qf[g][kk] = *(const s16x8*)(Qb + (size_t)(qbase[g] + lo) * HD_ + kk * 32 + hi * 8);

  f32x4 O[2][4];
#pragma unroll
  for (int g = 0; g < 2; ++g)
#pragma unroll
    for (int nh = 0; nh < 4; ++nh) O[g][nh] = (f32x4){0.f, 0.f, 0.f, 0.f};
  float mrun[2] = {-1e30f, -1e30f}, lrun[2] = {0.f, 0.f};   // lrun: per-lane partial

  // 64-kv body; common path has no cross-lane ops
  auto process = [&](int kv0, int sub, bool g0act) {
    const unsigned short* Kbuf = Kl + sub * 4096;
    const unsigned short* Vbuf = Vl + sub * 4096;
    f32x4 p[2][4];
#pragma unroll
    for (int g = 0; g < 2; ++g)
#pragma unroll
      for (int n = 0; n < 4; ++n) p[g][n] = (f32x4){0.f, 0.f, 0.f, 0.f};
#pragma unroll
    for (int kk = 0; kk < 2; ++kk) {
      s16x8 kf[4];
#pragma unroll
      for (int n = 0; n < 4; ++n)
        kf[n] = *(const s16x8*)&Kbuf[(n * 16 + lo) * 64 + 8 * ((kk * 4 + hi) ^ (lo & 7))];
      __builtin_amdgcn_s_setprio(1);
#pragma unroll
      for (int n = 0; n < 4; ++n)
        p[1][n] = __builtin_amdgcn_mfma_f32_16x16x32_bf16(kf[n], qf[1][kk], p[1][n], 0, 0, 0);
      if (g0act) {
#pragma unroll
        for (int n = 0; n < 4; ++n)
          p[0][n] = __builtin_amdgcn_mfma_f32_16x16x32_bf16(kf[n], qf[0][kk], p[0][n], 0, 0, 0);
      }
      __builtin_amdgcn_s_setprio(0);
    }

    union PU { unsigned int u[4]; s16x8 s; };
    PU pa[2][2];
#pragma unroll
    for (int g = 0; g < 2; ++g) {
      if (g == 0 && !g0act) continue;      // block-uniform skip
      if (kv0 + 63 > qbase[g]) {           // wave-uniform: diagonal tile only
        const int q = qbase[g] + lo;
#pragma unroll
        for (int n = 0; n < 4; ++n)
#pragma unroll
          for (int r = 0; r < 4; ++r) {
            int kv = kv0 + 32 * (n >> 1) + 8 * hi + 2 * r + (n & 1);
            p[g][n][r] = (kv <= q) ? p[g][n][r] : -1e30f;
          }
      }
      // lane-local max (partial row max over this lane's 16 kv)
      float mx = fmaxf(fmaxf(fmaxf(p[g][0][0], p[g][0][1]), fmaxf(p[g][0][2], p[g][0][3])),
                       fmaxf(fmaxf(p[g][1][0], p[g][1][1]), fmaxf(p[g][1][2], p[g][1][3])));
      mx = fmaxf(mx, fmaxf(fmaxf(fmaxf(p[g][2][0], p[g][2][1]), fmaxf(p[g][2][2], p[g][2][3])),
                           fmaxf(fmaxf(p[g][3][0], p[g][3][1]), fmaxf(p[g][3][2], p[g][3][3]))));
      // T13 defer-max: __all reduces across lanes -> no shfl in common path.
      // (row max <= thr iff every lane partial <= thr)
      const bool need = !__all(mx <= mrun[g] + 8.0f);
      if (need) {                          // rare: full row max + rescale
        mx = fmaxf(mx, __shfl_xor(mx, 16));
        mx = fmaxf(mx, __shfl_xor(mx, 32));
        float mnew = fmaxf(mrun[g], mx);
        float alpha = exp2f(mrun[g] - mnew);   // row-consistent (mrun, mx row-uniform)
        mrun[g] = mnew;
        lrun[g] *= alpha;                  // per-lane partial scales coherently
#pragma unroll
        for (int r = 0; r < 4; ++r) {
          float ar_ = __shfl(alpha, 4 * hi + r);
#pragma unroll
          for (int nh = 0; nh < 4; ++nh) O[g][nh][r] *= ar_;
        }
      }
      float sum = 0.f;
#pragma unroll
      for (int n = 0; n < 4; ++n)
#pragma unroll
        for (int r = 0; r < 4; ++r) {
          float e = exp2f(p[g][n][r] - mrun[g]);   // masked: exp2(-1e30)=0
          p[g][n][r] = e;
          sum += e;
        }
      lrun[g] += sum;                      // per-lane partial; reduce at epilogue
#pragma unroll
      for (int c = 0; c < 2; ++c)
#pragma unroll
        for (int r = 0; r < 4; ++r) {
          unsigned int pk;
          asm("v_cvt_pk_bf16_f32 %0, %1, %2"
              : "=v"(pk) : "v"(p[g][2 * c][r]), "v"(p[g][2 * c + 1][r]));
          pa[g][c].u[r] = pk;
        }
    }

#pragma unroll
    for (int c = 0; c < 2; ++c) {
      s16x8 vf[4];
#pragma unroll
      for (int nh = 0; nh < 4; ++nh)
        vf[nh] = *(const s16x8*)&Vbuf[(nh * 16 + lo) * 64 + 8 * ((4 * c + hi) ^ (lo & 7))];
      __builtin_amdgcn_s_setprio(1);
#pragma unroll
      for (int nh = 0; nh < 4; ++nh)
        O[1][nh] = __builtin_amdgcn_mfma_f32_16x16x32_bf16(pa[1][c].s, vf[nh], O[1][nh], 0, 0, 0);
      if (g0act) {
#pragma unroll
        for (int nh = 0; nh < 4; ++nh)
          O[0][nh] = __builtin_amdgcn_mfma_f32_16x16x32_bf16(pa[0][c].s, vf[nh], O[0][nh], 0, 0, 0);
      }
      __builtin_amdgcn_s_setprio(0);
    }
  };

  // prologue: visit 0 (tiles 0,1) -> LDS
  u16x8 rk00 = *(const u16x8*)ksrc0;
  u16x8 rk01 = *(const u16x8*)ksrc1;
  u16x8 rk10 = *(const u16x8*)(ksrc0 + (size_t)64 * HD_);
  u16x8 rk11 = *(const u16x8*)(ksrc1 + (size_t)64 * HD_);
  u16x8 rv00 = *(const u16x8*)vsrc0;
  u16x8 rv01 = *(const u16x8*)vsrc1;
  u16x8 rv10 = *(const u16x8*)(vsrc0 + 64);
  u16x8 rv11 = *(const u16x8*)(vsrc1 + 64);
  *(u16x8*)&Kl[kd0] = rk00;        *(u16x8*)&Kl[kd1] = rk01;
  *(u16x8*)&Kl[4096 + kd0] = rk10; *(u16x8*)&Kl[4096 + kd1] = rk11;
  *(u16x8*)&Vl[vd0] = rv00;        *(u16x8*)&Vl[vd1] = rv01;
  *(u16x8*)&Vl[4096 + vd0] = rv10; *(u16x8*)&Vl[4096 + vd1] = rv11;
  __syncthreads();

  for (int kt = 0; kt < nv; ++kt) {
    const int base = kt * 128;
    const bool pf = (kt + 1 < nv);
    if (pf) {                              // T14: issue loads BEFORE compute
      const int nb = base + 128;
      rk00 = *(const u16x8*)(ksrc0 + (size_t)nb * HD_);
      rk01 = *(const u16x8*)(ksrc1 + (size_t)nb * HD_);
      rk10 = *(const u16x8*)(ksrc0 + (size_t)(nb + 64) * HD_);
      rk11 = *(const u16x8*)(ksrc1 + (size_t)(nb + 64) * HD_);
      rv00 = *(const u16x8*)(vsrc0 + nb);
      rv01 = *(const u16x8*)(vsrc1 + nb);
      rv10 = *(const u16x8*)(vsrc0 + nb + 64);
      rv11 = *(const u16x8*)(vsrc1 + nb + 64);
    }

    process(base, 0, 2 * kt < e0);              // sub-tile 0 (always < ex1)
    if (2 * kt + 1 < ex1)
      process(base + 64, 1, 2 * kt + 1 < e0);   // sub-tile 1

    if (pf) {                              // T14: write AFTER compute
      __syncthreads();                     // all reads of Kl/Vl done
      *(u16x8*)&Kl[kd0] = rk00;        *(u16x8*)&Kl[kd1] = rk01;
      *(u16x8*)&Kl[4096 + kd0] = rk10; *(u16x8*)&Kl[4096 + kd1] = rk11;
      *(u16x8*)&Vl[vd0] = rv00;        *(u16x8*)&Vl[vd1] = rv01;
      *(u16x8*)&Vl[4096 + vd0] = rv10; *(u16x8*)&Vl[4096 + vd1] = rv11;
      __syncthreads();                     // staged visible
    }
  }

  // epilogue: reduce per-lane lrun partials once, then store ctx bf16
#pragma unroll
  for (int g = 0; g < 2; ++g) {
    float lr = lrun[g];
    lr += __shfl_xor(lr, 16);
    lr += __shfl_xor(lr, 32);              // row sum (uniform across hi)
#pragma unroll
    for (int r = 0; r < 4; ++r) {
      float li = 1.0f / __shfl(lr, 4 * hi + r);
      int qg = qbase[g] + 4 * hi + r;
#pragma unroll
      for (int nh = 0; nh < 4; ++nh) {
        int hd = nh * 16 + lo;
        ctx[(((size_t)(bb * S_ + qg)) * H_ + h) * HD_ + hd] = f2bf(O[g][nh][r] * li);
      }
    }
  }
}

// ---------------------------------------------------------------- launch
extern "C" void kernel_launch(void* const* d_in, const int* in_sizes, int n_in,
                              void* d_out, int out_size, void* d_ws, size_t ws_size,
                              hipStream_t stream) {
  const float* x      = (const float*)d_in[0];
  const float* W_attn = (const float*)d_in[1];
  const float* b_attn = (const float*)d_in[2];
  const float* W_proj = (const float*)d_in[3];
  const float* b_proj = (const float*)d_in[4];
  float* out = (float*)d_out;

  char* ws = (char*)d_ws;
  size_t off = 0;
  auto alloc = [&](size_t bytes) {
    char* p = ws + off;
    off += (bytes + 255) & ~(size_t)255;
    return p;
  };
  unsigned short* xb  = (unsigned short*)alloc((size_t)8192 * 1024 * 2);
  unsigned short* Wta = (unsigned short*)alloc((size_t)3072 * 1024 * 2);
  unsigned short* Wtp = (unsigned short*)alloc((size_t)1024 * 1024 * 2);
  unsigned short* Qh  = (unsigned short*)alloc((size_t)64 * 2048 * 64 * 2);
  unsigned short* Kh  = (unsigned short*)alloc((size_t)64 * 2048 * 64 * 2);
  unsigned short* Vh  = (unsigned short*)alloc((size_t)64 * 2048 * 64 * 2);
  unsigned short* Vt  = (unsigned short*)alloc((size_t)64 * 2048 * 64 * 2);
  unsigned short* ctx = (unsigned short*)alloc((size_t)8192 * 1024 * 2);

  k_cvt<<<dim3(2048), dim3(256), 0, stream>>>(x, xb, (8192 * 1024) / 4);
  k_tpose_cvt<<<dim3(48, 16), dim3(256), 0, stream>>>(W_attn, Wta, 1024, 3072);
  k_tpose_cvt<<<dim3(16, 16), dim3(256), 0, stream>>>(W_proj, Wtp, 1024, 1024);
  k_gemm_qkv<<<dim3(24, 64), dim3(256), 0, stream>>>(xb, Wta, b_attn, Qh, Kh, Vh);
  k_tpose_v<<<dim3(32, 64), dim3(256), 0, stream>>>(Vh, Vt);
  k_attn<<<dim3(1024), dim3(256), 0, stream>>>(Qh, Kh, Vt, ctx);
  k_gemm_proj<<<dim3(8, 64), dim3(256), 0, stream>>>(ctx, Wtp, b_proj, out, 1024);
}

// Round 11
// 177.972 us; speedup vs baseline: 1.1201x; 1.0235x over previous
//
#include <hip/hip_runtime.h>
#include <hip/hip_bf16.h>
#include <stdint.h>

// Problem constants: B=4, S=2048, D=1024, H=16, HD=64
#define B_  4
#define S_  2048
#define D_  1024
#define H_  16
#define HD_ 64

typedef __attribute__((ext_vector_type(8))) short          s16x8;   // MFMA A/B frag (8 bf16)
typedef __attribute__((ext_vector_type(4))) float          f32x4;   // MFMA C/D frag
typedef __attribute__((ext_vector_type(8))) unsigned short u16x8;   // 16B bf16 chunk

__device__ __forceinline__ unsigned short f2bf(float f) {
  union { float f; unsigned int u; } v; v.f = f;
  unsigned int u = v.u;
  u += 0x7fffu + ((u >> 16) & 1u);       // RNE
  return (unsigned short)(u >> 16);
}

__device__ __forceinline__ float max3f(float a, float b, float c) {
  float d;
  asm("v_max3_f32 %0, %1, %2, %3" : "=v"(d) : "v"(a), "v"(b), "v"(c));
  return d;
}

// async global->LDS, 16B per lane; LDS dest = wave-uniform base + lane*16
#define GLDS16(g, l)                                                           \
  __builtin_amdgcn_global_load_lds(                                            \
      (const __attribute__((address_space(1))) void*)(g),                      \
      (__attribute__((address_space(3))) void*)(l), 16, 0, 0)

// ---------------------------------------------------------------- converts
__global__ void k_cvt(const float* __restrict__ src, unsigned short* __restrict__ dst, int n4) {
  int i = blockIdx.x * blockDim.x + threadIdx.x;
  int stride = gridDim.x * blockDim.x;
  for (int j = i; j < n4; j += stride) {
    float4 v = reinterpret_cast<const float4*>(src)[j];
    ushort4 o;
    o.x = f2bf(v.x); o.y = f2bf(v.y); o.z = f2bf(v.z); o.w = f2bf(v.w);
    reinterpret_cast<ushort4*>(dst)[j] = o;
  }
}

// fp32 [R][C] -> bf16 [C][R]   (weights -> B^T layout for gemm-BT)
__global__ void k_tpose_cvt(const float* __restrict__ src, unsigned short* __restrict__ dst,
                            int R, int C) {
  __shared__ unsigned short tile[64][72];
  int c0 = blockIdx.x * 64, r0 = blockIdx.y * 64;
  int tx = threadIdx.x & 63, ty = threadIdx.x >> 6;
#pragma unroll
  for (int i = 0; i < 16; ++i) {
    int r = ty * 16 + i;
    tile[r][tx] = f2bf(src[(size_t)(r0 + r) * C + c0 + tx]);
  }
  __syncthreads();
#pragma unroll
  for (int i = 0; i < 16; ++i) {
    int c = ty * 16 + i;
    dst[(size_t)(c0 + c) * R + r0 + tx] = tile[tx][c];
  }
}

// bf16 V [BH][S][HD] -> Vt [BH][HD][S]
__global__ void k_tpose_v(const unsigned short* __restrict__ src, unsigned short* __restrict__ dst) {
  __shared__ unsigned short tile[64][72];
  int s0 = blockIdx.x * 64, bh = blockIdx.y;
  int tx = threadIdx.x & 63, ty = threadIdx.x >> 6;
  const unsigned short* sb = src + (size_t)bh * S_ * HD_;
  unsigned short*       db = dst + (size_t)bh * S_ * HD_;
#pragma unroll
  for (int i = 0; i < 16; ++i) {
    int r = ty * 16 + i;
    tile[r][tx] = sb[(size_t)(s0 + r) * HD_ + tx];
  }
  __syncthreads();
#pragma unroll
  for (int i = 0; i < 16; ++i) {
    int hd = ty * 16 + i;
    db[(size_t)hd * S_ + s0 + tx] = tile[tx][hd];
  }
}

// ---------------------------------------------------------------- GEMM core
// (unchanged: global_load_lds width=16, linear LDS dest, source-side XOR
//  chunk swizzle, one barrier per K-step)
__device__ __forceinline__ void gemm_core(const unsigned short* __restrict__ A,
                                          const unsigned short* __restrict__ Bt,
                                          int K, int m0, int n0,
                                          unsigned short* sm, f32x4 acc[4][4]) {
  const int t = threadIdx.x;
  const int w = t >> 6, l = t & 63;
  const int wm = w >> 1, wn = w & 1;
  const int lo = l & 15, hi = l >> 4;

  const int ci0 = w * 64 + l, ci1 = ci0 + 256;
  const int rA0 = ci0 >> 2, cA0 = (ci0 & 3) ^ ((rA0 >> 1) & 3);
  const int rA1 = ci1 >> 2, cA1 = (ci1 & 3) ^ ((rA1 >> 1) & 3);
  const unsigned short* gA0 = A  + (size_t)(m0 + rA0) * K + cA0 * 8;
  const unsigned short* gA1 = A  + (size_t)(m0 + rA1) * K + cA1 * 8;
  const unsigned short* gB0 = Bt + (size_t)(n0 + rA0) * K + cA0 * 8;
  const unsigned short* gB1 = Bt + (size_t)(n0 + rA1) * K + cA1 * 8;
  const int ldsA0 = (w * 64) * 8;
  const int ldsA1 = (256 + w * 64) * 8;

#pragma unroll
  for (int m = 0; m < 4; ++m)
#pragma unroll
    for (int n = 0; n < 4; ++n)
      acc[m][n] = (f32x4){0.f, 0.f, 0.f, 0.f};

  const int NT = K >> 5;  // BK = 32

  {
    unsigned short* b = sm;
    GLDS16(gA0, b + ldsA0);
    GLDS16(gA1, b + ldsA1);
    GLDS16(gB0, b + 4096 + ldsA0);
    GLDS16(gB1, b + 4096 + ldsA1);
  }

  for (int kt = 0; kt < NT; ++kt) {
    __syncthreads();
    if (kt + 1 < NT) {
      unsigned short* b = sm + ((kt + 1) & 1) * 8192;
      const int ko = (kt + 1) << 5;
      GLDS16(gA0 + ko, b + ldsA0);
      GLDS16(gA1 + ko, b + ldsA1);
      GLDS16(gB0 + ko, b + 4096 + ldsA0);
      GLDS16(gB1 + ko, b + 4096 + ldsA1);
    }
    const unsigned short* Ab = sm + (kt & 1) * 8192;
    const unsigned short* Bb = Ab + 4096;
    s16x8 af[4], bfr[4];
#pragma unroll
    for (int m = 0; m < 4; ++m) {
      int row = wm * 64 + m * 16 + lo;
      af[m] = *(const s16x8*)(Ab + row * 32 + ((hi ^ ((row >> 1) & 3)) << 3));
    }
#pragma unroll
    for (int n = 0; n < 4; ++n) {
      int row = wn * 64 + n * 16 + lo;
      bfr[n] = *(const s16x8*)(Bb + row * 32 + ((hi ^ ((row >> 1) & 3)) << 3));
    }
    __builtin_amdgcn_s_setprio(1);
#pragma unroll
    for (int m = 0; m < 4; ++m)
#pragma unroll
      for (int n = 0; n < 4; ++n)
        acc[m][n] = __builtin_amdgcn_mfma_f32_16x16x32_bf16(af[m], bfr[n], acc[m][n], 0, 0, 0);
    __builtin_amdgcn_s_setprio(0);
  }
}

// GEMM1: qkv = x @ W_attn + b ; scatter into Q/K/V [B,H,S,HD] bf16.
// Round-11: 1-D grid, XCD owns a contiguous 3-x-tile N-slice -> 768 KB
// weight slice is L2-resident per XCD (weights re-read by 64 M-blocks).
__global__ __launch_bounds__(256, 3)
void k_gemm_qkv(const unsigned short* __restrict__ A, const unsigned short* __restrict__ Bt,
                const float* __restrict__ bias,
                unsigned short* __restrict__ Qh, unsigned short* __restrict__ Kh,
                unsigned short* __restrict__ Vh) {
  __shared__ unsigned short sm[2 * 8192];
  const int bid = blockIdx.x;               // 0..1535
  const int i = bid >> 3;                   // 0..191
  const int x = (bid & 7) * 3 + (i % 3);    // 0..23 (3 x-tiles per XCD)
  const int y = i / 3;                      // 0..63
  const int m0 = y * 128, n0 = x * 128;
  f32x4 acc[4][4];
  gemm_core(A, Bt, 1024, m0, n0, sm, acc);
  const int t = threadIdx.x, w = t >> 6, l = t & 63;
  const int wm = w >> 1, wn = w & 1, lo = l & 15, hi = l >> 4;
#pragma unroll
  for (int m = 0; m < 4; ++m)
#pragma unroll
    for (int n = 0; n < 4; ++n) {
      int col = n0 + wn * 64 + n * 16 + lo;           // 0..3071
      float bv = bias[col];
      int sel = col >> 10, cw = col & 1023, h = cw >> 6, hd = cw & 63;
      float scl = (sel == 0) ? 0.18033688011112042f : 1.0f;  // log2(e)/8
      unsigned short* dst = (sel == 0) ? Qh : ((sel == 1) ? Kh : Vh);
#pragma unroll
      for (int r = 0; r < 4; ++r) {
        int row = m0 + wm * 64 + m * 16 + hi * 4 + r;
        int b = row >> 11, s = row & 2047;
        dst[(((size_t)b * H_ + h) * S_ + s) * HD_ + hd] = f2bf((acc[m][n][r] + bv) * scl);
      }
    }
}

// GEMM2: out = ctx @ W_proj + b ; fp32 out. 1-D grid, 1 x-tile per XCD.
__global__ __launch_bounds__(256, 3)
void k_gemm_proj(const unsigned short* __restrict__ A, const unsigned short* __restrict__ Bt,
                 const float* __restrict__ bias, float* __restrict__ C, int N) {
  __shared__ unsigned short sm[2 * 8192];
  const int bid = blockIdx.x;               // 0..511
  const int x = bid & 7, y = bid >> 3;      // x: 1 per XCD; y: 0..63
  const int m0 = y * 128, n0 = x * 128;
  f32x4 acc[4][4];
  gemm_core(A, Bt, 1024, m0, n0, sm, acc);
  const int t = threadIdx.x, w = t >> 6, l = t & 63;
  const int wm = w >> 1, wn = w & 1, lo = l & 15, hi = l >> 4;
#pragma unroll
  for (int m = 0; m < 4; ++m)
#pragma unroll
    for (int n = 0; n < 4; ++n) {
      int col = n0 + wn * 64 + n * 16 + lo;
      float bv = bias[col];
#pragma unroll
      for (int r = 0; r < 4; ++r) {
        int row = m0 + wm * 64 + m * 16 + hi * 4 + r;
        C[(size_t)row * N + col] = acc[m][n][r] + bv;
      }
    }
}

// ---------------------------------------------------------------- attention
// Swapped QK^T (mfma(K,Q)); K rows LDS-permuted so the PV A-fragment is
// lane-resident after cvt_pk; G4 XOR chunk swizzle on K/V (0 conflicts);
// XCD swizzle; (jp, 31-jp) pairing; KVBLK=128; lane-local softmax (round 10).
// Round-11 VALU trim (VALU is the binding pipe, 63% busy):
//  - persistent zero f32x4 as the kk=0 MFMA C-operand: kills the 16 v_mov
//    zero-inits per g per call (compiler hoists fz once).
//  - v_max3_f32 tree: 15-op fmax chain -> 8 ops (T17).
__global__ __launch_bounds__(256, 2)
void k_attn(const unsigned short* __restrict__ Qh, const unsigned short* __restrict__ Kh,
            const unsigned short* __restrict__ Vt, unsigned short* __restrict__ ctx) {
  __shared__ unsigned short Kl[2 * 4096];   // [sub][slot 64][hd 64], swizzled
  __shared__ unsigned short Vl[2 * 4096];   // [sub][hd 64][kv 64],  swizzled
  const int bid = blockIdx.x;
  const int g8  = bid & 7;                  // target XCD
  const int idx = bid >> 3;                 // 0..127
  const int bh  = g8 * 8 + (idx & 7);       // 8 heads per XCD
  const int jp  = idx >> 3;                 // pair index 0..15
  const int t = threadIdx.x, w = t >> 6, l = t & 63, lo = l & 15, hi = l >> 4;
  const unsigned short* Qb = Qh + (size_t)bh * S_ * HD_;
  const unsigned short* Kb = Kh + (size_t)bh * S_ * HD_;
  const unsigned short* Vb = Vt + (size_t)bh * S_ * HD_;   // [HD][S]
  const int bb = bh >> 4, h = bh & 15;

  const int r0s = t >> 3, schunk = t & 7, r1s = r0s + 32;
  const int ks0 = ((r0s & 1) << 4) | ((r0s >> 1) & 15);            // r0s<32
  const int ks1 = 32 | ((r1s & 1) << 4) | ((r1s >> 1) & 15);
  const int kd0 = ks0 * 64 + 8 * (schunk ^ (ks0 & 7));
  const int kd1 = ks1 * 64 + 8 * (schunk ^ (ks1 & 7));
  const int vd0 = r0s * 64 + 8 * (schunk ^ (r0s & 7));
  const int vd1 = r1s * 64 + 8 * (schunk ^ (r1s & 7));
  const unsigned short* ksrc0 = Kb + r0s * HD_ + schunk * 8;          // + kv*HD_
  const unsigned short* ksrc1 = Kb + r1s * HD_ + schunk * 8;
  const unsigned short* vsrc0 = Vb + (size_t)r0s * S_ + schunk * 8;   // + kv
  const unsigned short* vsrc1 = Vb + (size_t)r1s * S_ + schunk * 8;

  const int e0  = jp + 1;                   // subtile-0 extent (64-tiles)
  const int ex1 = 32 - jp;                  // subtile-1 extent (64-tiles)
  const int nv  = (ex1 + 1) >> 1;           // 128-kv visits: 9..16

  s16x8 qf[2][2];
  int qbase[2];
  qbase[0] = 64 * jp        + w * 16;
  qbase[1] = 64 * (31 - jp) + w * 16;
#pragma unroll
  for (int g = 0; g < 2; ++g)
#pragma unroll
    for (int kk = 0; kk < 2; ++kk)
      qf[g][kk] = *(const s16x8*)(Qb + (size_t)(qbase[g] + lo) * HD_ + kk * 32 + hi * 8);

  f32x4 O[2][4];
#pragma unroll
  for (int g = 0; g < 2; ++g)
#pragma unroll
    for (int nh = 0; nh < 4; ++nh) O[g][nh] = (f32x4){0.f, 0.f, 0.f, 0.f};
  float mrun[2] = {-1e30f, -1e30f}, lrun[2] = {0.f, 0.f};   // lrun: per-lane partial
  const f32x4 fz = {0.f, 0.f, 0.f, 0.f};    // persistent MFMA zero C-in (hoisted)

  // 64-kv body; common path has no cross-lane ops
  auto process = [&](int kv0, int sub, bool g0act) {
    const unsigned short* Kbuf = Kl + sub * 4096;
    const unsigned short* Vbuf = Vl + sub * 4096;
    f32x4 p[2][4];
    {                                        // kk = 0: C-in = fz (no zero-init movs)
      s16x8 kf[4];
#pragma unroll
      for (int n = 0; n < 4; ++n)
        kf[n] = *(const s16x8*)&Kbuf[(n * 16 + lo) * 64 + 8 * (hi ^ (lo & 7))];
      __builtin_amdgcn_s_setprio(1);
#pragma unroll
      for (int n = 0; n < 4; ++n)
        p[1][n] = __builtin_amdgcn_mfma_f32_16x16x32_bf16(kf[n], qf[1][0], fz, 0, 0, 0);
      if (g0act) {
#pragma unroll
        for (int n = 0; n < 4; ++n)
          p[0][n] = __builtin_amdgcn_mfma_f32_16x16x32_bf16(kf[n], qf[0][0], fz, 0, 0, 0);
      }
      __builtin_amdgcn_s_setprio(0);
    }
    {                                        // kk = 1: accumulate
      s16x8 kf[4];
#pragma unroll
      for (int n = 0; n < 4; ++n)
        kf[n] = *(const s16x8*)&Kbuf[(n * 16 + lo) * 64 + 8 * ((4 + hi) ^ (lo & 7))];
      __builtin_amdgcn_s_setprio(1);
#pragma unroll
      for (int n = 0; n < 4; ++n)
        p[1][n] = __builtin_amdgcn_mfma_f32_16x16x32_bf16(kf[n], qf[1][1], p[1][n], 0, 0, 0);
      if (g0act) {
#pragma unroll
        for (int n = 0; n < 4; ++n)
          p[0][n] = __builtin_amdgcn_mfma_f32_16x16x32_bf16(kf[n], qf[0][1], p[0][n], 0, 0, 0);
      }
      __builtin_amdgcn_s_setprio(0);
    }

    union PU { unsigned int u[4]; s16x8 s; };
    PU pa[2][2];
#pragma unroll
    for (int g = 0; g < 2; ++g) {
      if (g == 0 && !g0act) continue;      // block-uniform skip
      if (kv0 + 63 > qbase[g]) {           // wave-uniform: diagonal tile only
        const int q = qbase[g] + lo;
#pragma unroll
        for (int n = 0; n < 4; ++n)
#pragma unroll
          for (int r = 0; r < 4; ++r) {
            int kv = kv0 + 32 * (n >> 1) + 8 * hi + 2 * r + (n & 1);
            p[g][n][r] = (kv <= q) ? p[g][n][r] : -1e30f;
          }
      }
      // lane-local max via v_max3 tree (8 ops, was 15 fmax)
      float a0 = max3f(p[g][0][0], p[g][0][1], p[g][0][2]);
      float a1 = max3f(p[g][0][3], p[g][1][0], p[g][1][1]);
      float a2 = max3f(p[g][1][2], p[g][1][3], p[g][2][0]);
      float a3 = max3f(p[g][2][1], p[g][2][2], p[g][2][3]);
      float a4 = max3f(p[g][3][0], p[g][3][1], p[g][3][2]);
      float mx = fmaxf(max3f(a0, a1, a2), max3f(a3, a4, p[g][3][3]));
      // T13 defer-max: __all reduces across lanes -> no shfl in common path
      const bool need = !__all(mx <= mrun[g] + 8.0f);
      if (need) {                          // rare: full row max + rescale
        mx = fmaxf(mx, __shfl_xor(mx, 16));
        mx = fmaxf(mx, __shfl_xor(mx, 32));
        float mnew = fmaxf(mrun[g], mx);
        float alpha = exp2f(mrun[g] - mnew);
        mrun[g] = mnew;
        lrun[g] *= alpha;                  // per-lane partial scales coherently
#pragma unroll
        for (int r = 0; r < 4; ++r) {
          float ar_ = __shfl(alpha, 4 * hi + r);
#pragma unroll
          for (int nh = 0; nh < 4; ++nh) O[g][nh][r] *= ar_;
        }
      }
      float sum = 0.f;
#pragma unroll
      for (int n = 0; n < 4; ++n)
#pragma unroll
        for (int r = 0; r < 4; ++r) {
          float e = exp2f(p[g][n][r] - mrun[g]);   // masked: exp2(-1e30)=0
          p[g][n][r] = e;
          sum += e;
        }
      lrun[g] += sum;                      // per-lane partial; reduce at epilogue
#pragma unroll
      for (int c = 0; c < 2; ++c)
#pragma unroll
        for (int r = 0; r < 4; ++r) {
          unsigned int pk;
          asm("v_cvt_pk_bf16_f32 %0, %1, %2"
              : "=v"(pk) : "v"(p[g][2 * c][r]), "v"(p[g][2 * c + 1][r]));
          pa[g][c].u[r] = pk;
        }
    }

#pragma unroll
    for (int c = 0; c < 2; ++c) {
      s16x8 vf[4];
#pragma unroll
      for (int nh = 0; nh < 4; ++nh)
        vf[nh] = *(const s16x8*)&Vbuf[(nh * 16 + lo) * 64 + 8 * ((4 * c + hi) ^ (lo & 7))];
      __builtin_amdgcn_s_setprio(1);
#pragma unroll
      for (int nh = 0; nh < 4; ++nh)
        O[1][nh] = __builtin_amdgcn_mfma_f32_16x16x32_bf16(pa[1][c].s, vf[nh], O[1][nh], 0, 0, 0);
      if (g0act) {
#pragma unroll
        for (int nh = 0; nh < 4; ++nh)
          O[0][nh] = __builtin_amdgcn_mfma_f32_16x16x32_bf16(pa[0][c].s, vf[nh], O[0][nh], 0, 0, 0);
      }
      __builtin_amdgcn_s_setprio(0);
    }
  };

  // prologue: visit 0 (tiles 0,1) -> LDS
  u16x8 rk00 = *(const u16x8*)ksrc0;
  u16x8 rk01 = *(const u16x8*)ksrc1;
  u16x8 rk10 = *(const u16x8*)(ksrc0 + (size_t)64 * HD_);
  u16x8 rk11 = *(const u16x8*)(ksrc1 + (size_t)64 * HD_);
  u16x8 rv00 = *(const u16x8*)vsrc0;
  u16x8 rv01 = *(const u16x8*)vsrc1;
  u16x8 rv10 = *(const u16x8*)(vsrc0 + 64);
  u16x8 rv11 = *(const u16x8*)(vsrc1 + 64);
  *(u16x8*)&Kl[kd0] = rk00;        *(u16x8*)&Kl[kd1] = rk01;
  *(u16x8*)&Kl[4096 + kd0] = rk10; *(u16x8*)&Kl[4096 + kd1] = rk11;
  *(u16x8*)&Vl[vd0] = rv00;        *(u16x8*)&Vl[vd1] = rv01;
  *(u16x8*)&Vl[4096 + vd0] = rv10; *(u16x8*)&Vl[4096 + vd1] = rv11;
  __syncthreads();

  for (int kt = 0; kt < nv; ++kt) {
    const int base = kt * 128;
    const bool pf = (kt + 1 < nv);
    if (pf) {                              // T14: issue loads BEFORE compute
      const int nb = base + 128;
      rk00 = *(const u16x8*)(ksrc0 + (size_t)nb * HD_);
      rk01 = *(const u16x8*)(ksrc1 + (size_t)nb * HD_);
      rk10 = *(const u16x8*)(ksrc0 + (size_t)(nb + 64) * HD_);
      rk11 = *(const u16x8*)(ksrc1 + (size_t)(nb + 64) * HD_);
      rv00 = *(const u16x8*)(vsrc0 + nb);
      rv01 = *(const u16x8*)(vsrc1 + nb);
      rv10 = *(const u16x8*)(vsrc0 + nb + 64);
      rv11 = *(const u16x8*)(vsrc1 + nb + 64);
    }

    process(base, 0, 2 * kt < e0);              // sub-tile 0 (always < ex1)
    if (2 * kt + 1 < ex1)
      process(base + 64, 1, 2 * kt + 1 < e0);   // sub-tile 1

    if (pf) {                              // T14: write AFTER compute
      __syncthreads();                     // all reads of Kl/Vl done
      *(u16x8*)&Kl[kd0] = rk00;        *(u16x8*)&Kl[kd1] = rk01;
      *(u16x8*)&Kl[4096 + kd0] = rk10; *(u16x8*)&Kl[4096 + kd1] = rk11;
      *(u16x8*)&Vl[vd0] = rv00;        *(u16x8*)&Vl[vd1] = rv01;
      *(u16x8*)&Vl[4096 + vd0] = rv10; *(u16x8*)&Vl[4096 + vd1] = rv11;
      __syncthreads();                     // staged visible
    }
  }

  // epilogue: reduce per-lane lrun partials once, then store ctx bf16
#pragma unroll
  for (int g = 0; g < 2; ++g) {
    float lr = lrun[g];
    lr += __shfl_xor(lr, 16);
    lr += __shfl_xor(lr, 32);              // row sum (uniform across hi)
#pragma unroll
    for (int r = 0; r < 4; ++r) {
      float li = 1.0f / __shfl(lr, 4 * hi + r);
      int qg = qbase[g] + 4 * hi + r;
#pragma unroll
      for (int nh = 0; nh < 4; ++nh) {
        int hd = nh * 16 + lo;
        ctx[(((size_t)(bb * S_ + qg)) * H_ + h) * HD_ + hd] = f2bf(O[g][nh][r] * li);
      }
    }
  }
}

// ---------------------------------------------------------------- launch
extern "C" void kernel_launch(void* const* d_in, const int* in_sizes, int n_in,
                              void* d_out, int out_size, void* d_ws, size_t ws_size,
                              hipStream_t stream) {
  const float* x      = (const float*)d_in[0];
  const float* W_attn = (const float*)d_in[1];
  const float* b_attn = (const float*)d_in[2];
  const float* W_proj = (const float*)d_in[3];
  const float* b_proj = (const float*)d_in[4];
  float* out = (float*)d_out;

  char* ws = (char*)d_ws;
  size_t off = 0;
  auto alloc = [&](size_t bytes) {
    char* p = ws + off;
    off += (bytes + 255) & ~(size_t)255;
    return p;
  };
  unsigned short* xb  = (unsigned short*)alloc((size_t)8192 * 1024 * 2);
  unsigned short* Wta = (unsigned short*)alloc((size_t)3072 * 1024 * 2);
  unsigned short* Wtp = (unsigned short*)alloc((size_t)1024 * 1024 * 2);
  unsigned short* Qh  = (unsigned short*)alloc((size_t)64 * 2048 * 64 * 2);
  unsigned short* Kh  = (unsigned short*)alloc((size_t)64 * 2048 * 64 * 2);
  unsigned short* Vh  = (unsigned short*)alloc((size_t)64 * 2048 * 64 * 2);
  unsigned short* Vt  = (unsigned short*)alloc((size_t)64 * 2048 * 64 * 2);
  unsigned short* ctx = (unsigned short*)alloc((size_t)8192 * 1024 * 2);

  k_cvt<<<dim3(2048), dim3(256), 0, stream>>>(x, xb, (8192 * 1024) / 4);
  k_tpose_cvt<<<dim3(48, 16), dim3(256), 0, stream>>>(W_attn, Wta, 1024, 3072);
  k_tpose_cvt<<<dim3(16, 16), dim3(256), 0, stream>>>(W_proj, Wtp, 1024, 1024);
  k_gemm_qkv<<<dim3(1536), dim3(256), 0, stream>>>(xb, Wta, b_attn, Qh, Kh, Vh);
  k_tpose_v<<<dim3(32, 64), dim3(256), 0, stream>>>(Vh, Vt);
  k_attn<<<dim3(1024), dim3(256), 0, stream>>>(Qh, Kh, Vt, ctx);
  k_gemm_proj<<<dim3(512), dim3(256), 0, stream>>>(ctx, Wtp, b_proj, out, 1024);
}

// Round 12
// 172.421 us; speedup vs baseline: 1.1561x; 1.0322x over previous
//
#include <hip/hip_runtime.h>
#include <hip/hip_bf16.h>
#include <stdint.h>

// Problem constants: B=4, S=2048, D=1024, H=16, HD=64
#define B_  4
#define S_  2048
#define D_  1024
#define H_  16
#define HD_ 64

typedef __attribute__((ext_vector_type(8))) short          s16x8;   // MFMA A/B frag (8 bf16)
typedef __attribute__((ext_vector_type(4))) float          f32x4;   // MFMA C/D frag
typedef __attribute__((ext_vector_type(8))) unsigned short u16x8;   // 16B bf16 chunk

__device__ __forceinline__ unsigned short f2bf(float f) {
  union { float f; unsigned int u; } v; v.f = f;
  unsigned int u = v.u;
  u += 0x7fffu + ((u >> 16) & 1u);       // RNE
  return (unsigned short)(u >> 16);
}

__device__ __forceinline__ float max3f(float a, float b, float c) {
  float d;
  asm("v_max3_f32 %0, %1, %2, %3" : "=v"(d) : "v"(a), "v"(b), "v"(c));
  return d;
}

// bare v_exp_f32 (2^x). exp2f() without -ffast-math goes through OCML with
// range/denorm guards (~5-8 instrs); the builtin is the single instruction
// and the compiler still knows the trans-op hazard (unlike raw asm).
#if __has_builtin(__builtin_amdgcn_exp2f)
#define EXP2(x) __builtin_amdgcn_exp2f(x)
#else
#define EXP2(x) exp2f(x)
#endif

// async global->LDS, 16B per lane; LDS dest = wave-uniform base + lane*16
#define GLDS16(g, l)                                                           \
  __builtin_amdgcn_global_load_lds(                                            \
      (const __attribute__((address_space(1))) void*)(g),                      \
      (__attribute__((address_space(3))) void*)(l), 16, 0, 0)

// ---------------------------------------------------------------- converts
__global__ void k_cvt(const float* __restrict__ src, unsigned short* __restrict__ dst, int n4) {
  int i = blockIdx.x * blockDim.x + threadIdx.x;
  int stride = gridDim.x * blockDim.x;
  for (int j = i; j < n4; j += stride) {
    float4 v = reinterpret_cast<const float4*>(src)[j];
    ushort4 o;
    o.x = f2bf(v.x); o.y = f2bf(v.y); o.z = f2bf(v.z); o.w = f2bf(v.w);
    reinterpret_cast<ushort4*>(dst)[j] = o;
  }
}

// fp32 [R][C] -> bf16 [C][R]   (weights -> B^T layout for gemm-BT)
__global__ void k_tpose_cvt(const float* __restrict__ src, unsigned short* __restrict__ dst,
                            int R, int C) {
  __shared__ unsigned short tile[64][72];
  int c0 = blockIdx.x * 64, r0 = blockIdx.y * 64;
  int tx = threadIdx.x & 63, ty = threadIdx.x >> 6;
#pragma unroll
  for (int i = 0; i < 16; ++i) {
    int r = ty * 16 + i;
    tile[r][tx] = f2bf(src[(size_t)(r0 + r) * C + c0 + tx]);
  }
  __syncthreads();
#pragma unroll
  for (int i = 0; i < 16; ++i) {
    int c = ty * 16 + i;
    dst[(size_t)(c0 + c) * R + r0 + tx] = tile[tx][c];
  }
}

// bf16 V [BH][S][HD] -> Vt [BH][HD][S]
__global__ void k_tpose_v(const unsigned short* __restrict__ src, unsigned short* __restrict__ dst) {
  __shared__ unsigned short tile[64][72];
  int s0 = blockIdx.x * 64, bh = blockIdx.y;
  int tx = threadIdx.x & 63, ty = threadIdx.x >> 6;
  const unsigned short* sb = src + (size_t)bh * S_ * HD_;
  unsigned short*       db = dst + (size_t)bh * S_ * HD_;
#pragma unroll
  for (int i = 0; i < 16; ++i) {
    int r = ty * 16 + i;
    tile[r][tx] = sb[(size_t)(s0 + r) * HD_ + tx];
  }
  __syncthreads();
#pragma unroll
  for (int i = 0; i < 16; ++i) {
    int hd = ty * 16 + i;
    db[(size_t)hd * S_ + s0 + tx] = tile[tx][hd];
  }
}

// ---------------------------------------------------------------- GEMM core
// (unchanged: global_load_lds width=16, linear LDS dest, source-side XOR
//  chunk swizzle, one barrier per K-step)
__device__ __forceinline__ void gemm_core(const unsigned short* __restrict__ A,
                                          const unsigned short* __restrict__ Bt,
                                          int K, int m0, int n0,
                                          unsigned short* sm, f32x4 acc[4][4]) {
  const int t = threadIdx.x;
  const int w = t >> 6, l = t & 63;
  const int wm = w >> 1, wn = w & 1;
  const int lo = l & 15, hi = l >> 4;

  const int ci0 = w * 64 + l, ci1 = ci0 + 256;
  const int rA0 = ci0 >> 2, cA0 = (ci0 & 3) ^ ((rA0 >> 1) & 3);
  const int rA1 = ci1 >> 2, cA1 = (ci1 & 3) ^ ((rA1 >> 1) & 3);
  const unsigned short* gA0 = A  + (size_t)(m0 + rA0) * K + cA0 * 8;
  const unsigned short* gA1 = A  + (size_t)(m0 + rA1) * K + cA1 * 8;
  const unsigned short* gB0 = Bt + (size_t)(n0 + rA0) * K + cA0 * 8;
  const unsigned short* gB1 = Bt + (size_t)(n0 + rA1) * K + cA1 * 8;
  const int ldsA0 = (w * 64) * 8;
  const int ldsA1 = (256 + w * 64) * 8;

#pragma unroll
  for (int m = 0; m < 4; ++m)
#pragma unroll
    for (int n = 0; n < 4; ++n)
      acc[m][n] = (f32x4){0.f, 0.f, 0.f, 0.f};

  const int NT = K >> 5;  // BK = 32

  {
    unsigned short* b = sm;
    GLDS16(gA0, b + ldsA0);
    GLDS16(gA1, b + ldsA1);
    GLDS16(gB0, b + 4096 + ldsA0);
    GLDS16(gB1, b + 4096 + ldsA1);
  }

  for (int kt = 0; kt < NT; ++kt) {
    __syncthreads();
    if (kt + 1 < NT) {
      unsigned short* b = sm + ((kt + 1) & 1) * 8192;
      const int ko = (kt + 1) << 5;
      GLDS16(gA0 + ko, b + ldsA0);
      GLDS16(gA1 + ko, b + ldsA1);
      GLDS16(gB0 + ko, b + 4096 + ldsA0);
      GLDS16(gB1 + ko, b + 4096 + ldsA1);
    }
    const unsigned short* Ab = sm + (kt & 1) * 8192;
    const unsigned short* Bb = Ab + 4096;
    s16x8 af[4], bfr[4];
#pragma unroll
    for (int m = 0; m < 4; ++m) {
      int row = wm * 64 + m * 16 + lo;
      af[m] = *(const s16x8*)(Ab + row * 32 + ((hi ^ ((row >> 1) & 3)) << 3));
    }
#pragma unroll
    for (int n = 0; n < 4; ++n) {
      int row = wn * 64 + n * 16 + lo;
      bfr[n] = *(const s16x8*)(Bb + row * 32 + ((hi ^ ((row >> 1) & 3)) << 3));
    }
    __builtin_amdgcn_s_setprio(1);
#pragma unroll
    for (int m = 0; m < 4; ++m)
#pragma unroll
      for (int n = 0; n < 4; ++n)
        acc[m][n] = __builtin_amdgcn_mfma_f32_16x16x32_bf16(af[m], bfr[n], acc[m][n], 0, 0, 0);
    __builtin_amdgcn_s_setprio(0);
  }
}

// GEMM1: qkv = x @ W_attn + b ; scatter into Q/K/V [B,H,S,HD] bf16.
__global__ __launch_bounds__(256, 3)
void k_gemm_qkv(const unsigned short* __restrict__ A, const unsigned short* __restrict__ Bt,
                const float* __restrict__ bias,
                unsigned short* __restrict__ Qh, unsigned short* __restrict__ Kh,
                unsigned short* __restrict__ Vh) {
  __shared__ unsigned short sm[2 * 8192];
  const int bid = blockIdx.x;               // 0..1535
  const int i = bid >> 3;                   // 0..191
  const int x = (bid & 7) * 3 + (i % 3);    // 0..23 (3 x-tiles per XCD)
  const int y = i / 3;                      // 0..63
  const int m0 = y * 128, n0 = x * 128;
  f32x4 acc[4][4];
  gemm_core(A, Bt, 1024, m0, n0, sm, acc);
  const int t = threadIdx.x, w = t >> 6, l = t & 63;
  const int wm = w >> 1, wn = w & 1, lo = l & 15, hi = l >> 4;
#pragma unroll
  for (int m = 0; m < 4; ++m)
#pragma unroll
    for (int n = 0; n < 4; ++n) {
      int col = n0 + wn * 64 + n * 16 + lo;           // 0..3071
      float bv = bias[col];
      int sel = col >> 10, cw = col & 1023, h = cw >> 6, hd = cw & 63;
      float scl = (sel == 0) ? 0.18033688011112042f : 1.0f;  // log2(e)/8
      unsigned short* dst = (sel == 0) ? Qh : ((sel == 1) ? Kh : Vh);
#pragma unroll
      for (int r = 0; r < 4; ++r) {
        int row = m0 + wm * 64 + m * 16 + hi * 4 + r;
        int b = row >> 11, s = row & 2047;
        dst[(((size_t)b * H_ + h) * S_ + s) * HD_ + hd] = f2bf((acc[m][n][r] + bv) * scl);
      }
    }
}

// GEMM2: out = ctx @ W_proj + b ; fp32 out. 1-D grid, 1 x-tile per XCD.
__global__ __launch_bounds__(256, 3)
void k_gemm_proj(const unsigned short* __restrict__ A, const unsigned short* __restrict__ Bt,
                 const float* __restrict__ bias, float* __restrict__ C, int N) {
  __shared__ unsigned short sm[2 * 8192];
  const int bid = blockIdx.x;               // 0..511
  const int x = bid & 7, y = bid >> 3;      // x: 1 per XCD; y: 0..63
  const int m0 = y * 128, n0 = x * 128;
  f32x4 acc[4][4];
  gemm_core(A, Bt, 1024, m0, n0, sm, acc);
  const int t = threadIdx.x, w = t >> 6, l = t & 63;
  const int wm = w >> 1, wn = w & 1, lo = l & 15, hi = l >> 4;
#pragma unroll
  for (int m = 0; m < 4; ++m)
#pragma unroll
    for (int n = 0; n < 4; ++n) {
      int col = n0 + wn * 64 + n * 16 + lo;
      float bv = bias[col];
#pragma unroll
      for (int r = 0; r < 4; ++r) {
        int row = m0 + wm * 64 + m * 16 + hi * 4 + r;
        C[(size_t)row * N + col] = acc[m][n][r] + bv;
      }
    }
}

// ---------------------------------------------------------------- attention
// Swapped QK^T (mfma(K,Q)); K rows LDS-permuted so the PV A-fragment is
// lane-resident after cvt_pk; G4 XOR chunk swizzle on K/V (0 conflicts);
// XCD swizzle; (jp, 31-jp) pairing; KVBLK=128; lane-local softmax; fz C-in;
// v_max3 tree.
// Round-12: (a) bare v_exp_f32 via __builtin_amdgcn_exp2f -- exp2f without
// -ffast-math expands to OCML guarded code (~5-8 instrs), the dominant VALU
// block at 32 exps/g/call; (b) 4-way parallel sum partials (dep 32 -> 8+2).
__global__ __launch_bounds__(256, 2)
void k_attn(const unsigned short* __restrict__ Qh, const unsigned short* __restrict__ Kh,
            const unsigned short* __restrict__ Vt, unsigned short* __restrict__ ctx) {
  __shared__ unsigned short Kl[2 * 4096];   // [sub][slot 64][hd 64], swizzled
  __shared__ unsigned short Vl[2 * 4096];   // [sub][hd 64][kv 64],  swizzled
  const int bid = blockIdx.x;
  const int g8  = bid & 7;                  // target XCD
  const int idx = bid >> 3;                 // 0..127
  const int bh  = g8 * 8 + (idx & 7);       // 8 heads per XCD
  const int jp  = idx >> 3;                 // pair index 0..15
  const int t = threadIdx.x, w = t >> 6, l = t & 63, lo = l & 15, hi = l >> 4;
  const unsigned short* Qb = Qh + (size_t)bh * S_ * HD_;
  const unsigned short* Kb = Kh + (size_t)bh * S_ * HD_;
  const unsigned short* Vb = Vt + (size_t)bh * S_ * HD_;   // [HD][S]
  const int bb = bh >> 4, h = bh & 15;

  const int r0s = t >> 3, schunk = t & 7, r1s = r0s + 32;
  const int ks0 = ((r0s & 1) << 4) | ((r0s >> 1) & 15);            // r0s<32
  const int ks1 = 32 | ((r1s & 1) << 4) | ((r1s >> 1) & 15);
  const int kd0 = ks0 * 64 + 8 * (schunk ^ (ks0 & 7));
  const int kd1 = ks1 * 64 + 8 * (schunk ^ (ks1 & 7));
  const int vd0 = r0s * 64 + 8 * (schunk ^ (r0s & 7));
  const int vd1 = r1s * 64 + 8 * (schunk ^ (r1s & 7));
  const unsigned short* ksrc0 = Kb + r0s * HD_ + schunk * 8;          // + kv*HD_
  const unsigned short* ksrc1 = Kb + r1s * HD_ + schunk * 8;
  const unsigned short* vsrc0 = Vb + (size_t)r0s * S_ + schunk * 8;   // + kv
  const unsigned short* vsrc1 = Vb + (size_t)r1s * S_ + schunk * 8;

  const int e0  = jp + 1;                   // subtile-0 extent (64-tiles)
  const int ex1 = 32 - jp;                  // subtile-1 extent (64-tiles)
  const int nv  = (ex1 + 1) >> 1;           // 128-kv visits: 9..16

  s16x8 qf[2][2];
  int qbase[2];
  qbase[0] = 64 * jp        + w * 16;
  qbase[1] = 64 * (31 - jp) + w * 16;
#pragma unroll
  for (int g = 0; g < 2; ++g)
#pragma unroll
    for (int kk = 0; kk < 2; ++kk)
      qf[g][kk] = *(const s16x8*)(Qb + (size_t)(qbase[g] + lo) * HD_ + kk * 32 + hi * 8);

  f32x4 O[2][4];
#pragma unroll
  for (int g = 0; g < 2; ++g)
#pragma unroll
    for (int nh = 0; nh < 4; ++nh) O[g][nh] = (f32x4){0.f, 0.f, 0.f, 0.f};
  float mrun[2] = {-1e30f, -1e30f}, lrun[2] = {0.f, 0.f};   // lrun: per-lane partial
  const f32x4 fz = {0.f, 0.f, 0.f, 0.f};    // persistent MFMA zero C-in (hoisted)

  // 64-kv body; common path has no cross-lane ops
  auto process = [&](int kv0, int sub, bool g0act) {
    const unsigned short* Kbuf = Kl + sub * 4096;
    const unsigned short* Vbuf = Vl + sub * 4096;
    f32x4 p[2][4];
    {                                        // kk = 0: C-in = fz (no zero-init movs)
      s16x8 kf[4];
#pragma unroll
      for (int n = 0; n < 4; ++n)
        kf[n] = *(const s16x8*)&Kbuf[(n * 16 + lo) * 64 + 8 * (hi ^ (lo & 7))];
      __builtin_amdgcn_s_setprio(1);
#pragma unroll
      for (int n = 0; n < 4; ++n)
        p[1][n] = __builtin_amdgcn_mfma_f32_16x16x32_bf16(kf[n], qf[1][0], fz, 0, 0, 0);
      if (g0act) {
#pragma unroll
        for (int n = 0; n < 4; ++n)
          p[0][n] = __builtin_amdgcn_mfma_f32_16x16x32_bf16(kf[n], qf[0][0], fz, 0, 0, 0);
      }
      __builtin_amdgcn_s_setprio(0);
    }
    {                                        // kk = 1: accumulate
      s16x8 kf[4];
#pragma unroll
      for (int n = 0; n < 4; ++n)
        kf[n] = *(const s16x8*)&Kbuf[(n * 16 + lo) * 64 + 8 * ((4 + hi) ^ (lo & 7))];
      __builtin_amdgcn_s_setprio(1);
#pragma unroll
      for (int n = 0; n < 4; ++n)
        p[1][n] = __builtin_amdgcn_mfma_f32_16x16x32_bf16(kf[n], qf[1][1], p[1][n], 0, 0, 0);
      if (g0act) {
#pragma unroll
        for (int n = 0; n < 4; ++n)
          p[0][n] = __builtin_amdgcn_mfma_f32_16x16x32_bf16(kf[n], qf[0][1], p[0][n], 0, 0, 0);
      }
      __builtin_amdgcn_s_setprio(0);
    }

    union PU { unsigned int u[4]; s16x8 s; };
    PU pa[2][2];
#pragma unroll
    for (int g = 0; g < 2; ++g) {
      if (g == 0 && !g0act) continue;      // block-uniform skip
      if (kv0 + 63 > qbase[g]) {           // wave-uniform: diagonal tile only
        const int q = qbase[g] + lo;
#pragma unroll
        for (int n = 0; n < 4; ++n)
#pragma unroll
          for (int r = 0; r < 4; ++r) {
            int kv = kv0 + 32 * (n >> 1) + 8 * hi + 2 * r + (n & 1);
            p[g][n][r] = (kv <= q) ? p[g][n][r] : -1e30f;
          }
      }
      // lane-local max via v_max3 tree (8 ops)
      float a0 = max3f(p[g][0][0], p[g][0][1], p[g][0][2]);
      float a1 = max3f(p[g][0][3], p[g][1][0], p[g][1][1]);
      float a2 = max3f(p[g][1][2], p[g][1][3], p[g][2][0]);
      float a3 = max3f(p[g][2][1], p[g][2][2], p[g][2][3]);
      float a4 = max3f(p[g][3][0], p[g][3][1], p[g][3][2]);
      float mx = fmaxf(max3f(a0, a1, a2), max3f(a3, a4, p[g][3][3]));
      // T13 defer-max: __all reduces across lanes -> no shfl in common path
      const bool need = !__all(mx <= mrun[g] + 8.0f);
      if (need) {                          // rare: full row max + rescale
        mx = fmaxf(mx, __shfl_xor(mx, 16));
        mx = fmaxf(mx, __shfl_xor(mx, 32));
        float mnew = fmaxf(mrun[g], mx);
        float alpha = EXP2(mrun[g] - mnew);
        mrun[g] = mnew;
        lrun[g] *= alpha;                  // per-lane partial scales coherently
#pragma unroll
        for (int r = 0; r < 4; ++r) {
          float ar_ = __shfl(alpha, 4 * hi + r);
#pragma unroll
          for (int nh = 0; nh < 4; ++nh) O[g][nh][r] *= ar_;
        }
      }
      // exp2 via bare v_exp_f32; 4 parallel sum partials (dep 32 -> 8+2)
      const float mr = mrun[g];
      float s0 = 0.f, s1 = 0.f, s2 = 0.f, s3 = 0.f;
#pragma unroll
      for (int n = 0; n < 4; ++n) {
        float e0_ = EXP2(p[g][n][0] - mr);   // masked: exp2(-1e30)=0
        float e1_ = EXP2(p[g][n][1] - mr);
        float e2_ = EXP2(p[g][n][2] - mr);
        float e3_ = EXP2(p[g][n][3] - mr);
        p[g][n][0] = e0_; p[g][n][1] = e1_;
        p[g][n][2] = e2_; p[g][n][3] = e3_;
        s0 += e0_; s1 += e1_; s2 += e2_; s3 += e3_;
      }
      lrun[g] += (s0 + s1) + (s2 + s3);    // per-lane partial; reduce at epilogue
#pragma unroll
      for (int c = 0; c < 2; ++c)
#pragma unroll
        for (int r = 0; r < 4; ++r) {
          unsigned int pk;
          asm("v_cvt_pk_bf16_f32 %0, %1, %2"
              : "=v"(pk) : "v"(p[g][2 * c][r]), "v"(p[g][2 * c + 1][r]));
          pa[g][c].u[r] = pk;
        }
    }

#pragma unroll
    for (int c = 0; c < 2; ++c) {
      s16x8 vf[4];
#pragma unroll
      for (int nh = 0; nh < 4; ++nh)
        vf[nh] = *(const s16x8*)&Vbuf[(nh * 16 + lo) * 64 + 8 * ((4 * c + hi) ^ (lo & 7))];
      __builtin_amdgcn_s_setprio(1);
#pragma unroll
      for (int nh = 0; nh < 4; ++nh)
        O[1][nh] = __builtin_amdgcn_mfma_f32_16x16x32_bf16(pa[1][c].s, vf[nh], O[1][nh], 0, 0, 0);
      if (g0act) {
#pragma unroll
        for (int nh = 0; nh < 4; ++nh)
          O[0][nh] = __builtin_amdgcn_mfma_f32_16x16x32_bf16(pa[0][c].s, vf[nh], O[0][nh], 0, 0, 0);
      }
      __builtin_amdgcn_s_setprio(0);
    }
  };

  // prologue: visit 0 (tiles 0,1) -> LDS
  u16x8 rk00 = *(const u16x8*)ksrc0;
  u16x8 rk01 = *(const u16x8*)ksrc1;
  u16x8 rk10 = *(const u16x8*)(ksrc0 + (size_t)64 * HD_);
  u16x8 rk11 = *(const u16x8*)(ksrc1 + (size_t)64 * HD_);
  u16x8 rv00 = *(const u16x8*)vsrc0;
  u16x8 rv01 = *(const u16x8*)vsrc1;
  u16x8 rv10 = *(const u16x8*)(vsrc0 + 64);
  u16x8 rv11 = *(const u16x8*)(vsrc1 + 64);
  *(u16x8*)&Kl[kd0] = rk00;        *(u16x8*)&Kl[kd1] = rk01;
  *(u16x8*)&Kl[4096 + kd0] = rk10; *(u16x8*)&Kl[4096 + kd1] = rk11;
  *(u16x8*)&Vl[vd0] = rv00;        *(u16x8*)&Vl[vd1] = rv01;
  *(u16x8*)&Vl[4096 + vd0] = rv10; *(u16x8*)&Vl[4096 + vd1] = rv11;
  __syncthreads();

  for (int kt = 0; kt < nv; ++kt) {
    const int base = kt * 128;
    const bool pf = (kt + 1 < nv);
    if (pf) {                              // T14: issue loads BEFORE compute
      const int nb = base + 128;
      rk00 = *(const u16x8*)(ksrc0 + (size_t)nb * HD_);
      rk01 = *(const u16x8*)(ksrc1 + (size_t)nb * HD_);
      rk10 = *(const u16x8*)(ksrc0 + (size_t)(nb + 64) * HD_);
      rk11 = *(const u16x8*)(ksrc1 + (size_t)(nb + 64) * HD_);
      rv00 = *(const u16x8*)(vsrc0 + nb);
      rv01 = *(const u16x8*)(vsrc1 + nb);
      rv10 = *(const u16x8*)(vsrc0 + nb + 64);
      rv11 = *(const u16x8*)(vsrc1 + nb + 64);
    }

    process(base, 0, 2 * kt < e0);              // sub-tile 0 (always < ex1)
    if (2 * kt + 1 < ex1)
      process(base + 64, 1, 2 * kt + 1 < e0);   // sub-tile 1

    if (pf) {                              // T14: write AFTER compute
      __syncthreads();                     // all reads of Kl/Vl done
      *(u16x8*)&Kl[kd0] = rk00;        *(u16x8*)&Kl[kd1] = rk01;
      *(u16x8*)&Kl[4096 + kd0] = rk10; *(u16x8*)&Kl[4096 + kd1] = rk11;
      *(u16x8*)&Vl[vd0] = rv00;        *(u16x8*)&Vl[vd1] = rv01;
      *(u16x8*)&Vl[4096 + vd0] = rv10; *(u16x8*)&Vl[4096 + vd1] = rv11;
      __syncthreads();                     // staged visible
    }
  }

  // epilogue: reduce per-lane lrun partials once, then store ctx bf16
#pragma unroll
  for (int g = 0; g < 2; ++g) {
    float lr = lrun[g];
    lr += __shfl_xor(lr, 16);
    lr += __shfl_xor(lr, 32);              // row sum (uniform across hi)
#pragma unroll
    for (int r = 0; r < 4; ++r) {
      float li = 1.0f / __shfl(lr, 4 * hi + r);
      int qg = qbase[g] + 4 * hi + r;
#pragma unroll
      for (int nh = 0; nh < 4; ++nh) {
        int hd = nh * 16 + lo;
        ctx[(((size_t)(bb * S_ + qg)) * H_ + h) * HD_ + hd] = f2bf(O[g][nh][r] * li);
      }
    }
  }
}

// ---------------------------------------------------------------- launch
extern "C" void kernel_launch(void* const* d_in, const int* in_sizes, int n_in,
                              void* d_out, int out_size, void* d_ws, size_t ws_size,
                              hipStream_t stream) {
  const float* x      = (const float*)d_in[0];
  const float* W_attn = (const float*)d_in[1];
  const float* b_attn = (const float*)d_in[2];
  const float* W_proj = (const float*)d_in[3];
  const float* b_proj = (const float*)d_in[4];
  float* out = (float*)d_out;

  char* ws = (char*)d_ws;
  size_t off = 0;
  auto alloc = [&](size_t bytes) {
    char* p = ws + off;
    off += (bytes + 255) & ~(size_t)255;
    return p;
  };
  unsigned short* xb  = (unsigned short*)alloc((size_t)8192 * 1024 * 2);
  unsigned short* Wta = (unsigned short*)alloc((size_t)3072 * 1024 * 2);
  unsigned short* Wtp = (unsigned short*)alloc((size_t)1024 * 1024 * 2);
  unsigned short* Qh  = (unsigned short*)alloc((size_t)64 * 2048 * 64 * 2);
  unsigned short* Kh  = (unsigned short*)alloc((size_t)64 * 2048 * 64 * 2);
  unsigned short* Vh  = (unsigned short*)alloc((size_t)64 * 2048 * 64 * 2);
  unsigned short* Vt  = (unsigned short*)alloc((size_t)64 * 2048 * 64 * 2);
  unsigned short* ctx = (unsigned short*)alloc((size_t)8192 * 1024 * 2);

  k_cvt<<<dim3(2048), dim3(256), 0, stream>>>(x, xb, (8192 * 1024) / 4);
  k_tpose_cvt<<<dim3(48, 16), dim3(256), 0, stream>>>(W_attn, Wta, 1024, 3072);
  k_tpose_cvt<<<dim3(16, 16), dim3(256), 0, stream>>>(W_proj, Wtp, 1024, 1024);
  k_gemm_qkv<<<dim3(1536), dim3(256), 0, stream>>>(xb, Wta, b_attn, Qh, Kh, Vh);
  k_tpose_v<<<dim3(32, 64), dim3(256), 0, stream>>>(Vh, Vt);
  k_attn<<<dim3(1024), dim3(256), 0, stream>>>(Qh, Kh, Vt, ctx);
  k_gemm_proj<<<dim3(512), dim3(256), 0, stream>>>(ctx, Wtp, b_proj, out, 1024);
}